// Round 1
// baseline (14309.651 us; speedup 1.0000x reference)
//
#include <hip/hip_runtime.h>
#include <math.h>

// Problem constants
#define BB 8
#define CIN 6
#define NN 8192
#define KK 20
#define KSPLIT 4
#define KPT 5      // k per thread
#define CBLK 16    // channels per block iteration
#define NEG 0.2f
#define EPSV 1e-5f

__device__ __forceinline__ float lrelu(float v) { return fmaxf(v, NEG * v); }

// LDS layout for folded weights (float offsets)
constexpr int WT_O  = 0;      // 64*6 folded trans weights
constexpr int BT_O  = 384;    // 64  folded trans bias
constexpr int WP1_O = 448;    // 64*3 folded pos1
constexpr int BP1_O = 640;    // 64
constexpr int WP2_O = 704;    // 64*64 pos2 (raw)
constexpr int BP2_O = 4800;   // 64 pos_b2
constexpr int WG1_O = 4864;   // 16*6 folded gate1
constexpr int BG1_O = 4960;   // 16
constexpr int WG2_O = 4976;   // 16 gate_w2
constexpr int GB2_O = 4992;   // 1  gate_b2
constexpr int WA1_O = 4996;   // 16*6 folded attn1
constexpr int BA1_O = 5092;   // 16
constexpr int WA2_O = 5108;   // 64*16 attn_w2 (raw)
constexpr int AB2_O = 6132;   // 64 attn_b2
constexpr int WTOT  = 6196;

__global__ __launch_bounds__(256, 2)
void gsl_kernel(const float* __restrict__ x,
                const float* __restrict__ trans_w, const float* __restrict__ trans_g,
                const float* __restrict__ trans_b, const float* __restrict__ trans_m,
                const float* __restrict__ trans_v,
                const float* __restrict__ pos_w1, const float* __restrict__ pos_g,
                const float* __restrict__ pos_b, const float* __restrict__ pos_m,
                const float* __restrict__ pos_v, const float* __restrict__ pos_w2,
                const float* __restrict__ pos_b2,
                const float* __restrict__ gate_w1, const float* __restrict__ gate_g,
                const float* __restrict__ gate_b, const float* __restrict__ gate_m,
                const float* __restrict__ gate_v, const float* __restrict__ gate_w2,
                const float* __restrict__ gate_b2,
                const float* __restrict__ attn_w1, const float* __restrict__ attn_g,
                const float* __restrict__ attn_b, const float* __restrict__ attn_m,
                const float* __restrict__ attn_v, const float* __restrict__ attn_w2,
                const float* __restrict__ attn_b2,
                float* __restrict__ out)
{
    __shared__ float W[WTOT];
    const int tid = threadIdx.x;

    // ---- fold BN into weights, stage everything in LDS (once per block) ----
    for (int i = tid; i < 64 * 64; i += 256) W[WP2_O + i] = pos_w2[i];
    for (int i = tid; i < 64 * 16; i += 256) W[WA2_O + i] = attn_w2[i];
    if (tid < 64) {
        float s = trans_g[tid] * rsqrtf(trans_v[tid] + EPSV);
        #pragma unroll
        for (int i = 0; i < 6; ++i) W[WT_O + tid * 6 + i] = trans_w[tid * 6 + i] * s;
        W[BT_O + tid] = trans_b[tid] - trans_m[tid] * s;
        float sp = pos_g[tid] * rsqrtf(pos_v[tid] + EPSV);
        #pragma unroll
        for (int i = 0; i < 3; ++i) W[WP1_O + tid * 3 + i] = pos_w1[tid * 3 + i] * sp;
        W[BP1_O + tid] = pos_b[tid] - pos_m[tid] * sp;
        W[BP2_O + tid] = pos_b2[tid];
        W[AB2_O + tid] = attn_b2[tid];
    } else if (tid < 80) {
        int j = tid - 64;
        float sg = gate_g[j] * rsqrtf(gate_v[j] + EPSV);
        #pragma unroll
        for (int i = 0; i < 6; ++i) W[WG1_O + j * 6 + i] = gate_w1[j * 6 + i] * sg;
        W[BG1_O + j] = gate_b[j] - gate_m[j] * sg;
        W[WG2_O + j] = gate_w2[j];
    } else if (tid < 96) {
        int j = tid - 80;
        float sa = attn_g[j] * rsqrtf(attn_v[j] + EPSV);
        #pragma unroll
        for (int i = 0; i < 6; ++i) W[WA1_O + j * 6 + i] = attn_w1[j * 6 + i] * sa;
        W[BA1_O + j] = attn_b[j] - attn_m[j] * sa;
    } else if (tid == 96) {
        W[GB2_O] = gate_b2[0];
    }
    __syncthreads();

    // ---- main loop: thread = (b, n) x k-slice ----
    const int g = blockIdx.x * 256 + tid;
    const int point = g >> 2;          // (b, n) index
    const int ks = g & 3;              // k-split slice
    const int b = point >> 13;
    const int n = point & 8191;
    const float* xb = x + ((size_t)(b * CIN) * NN + n) * KK;
    const int k0 = ks * KPT;

    #pragma unroll
    for (int cb = 0; cb < 64 / CBLK; ++cb) {
        const int c0 = cb * CBLK;
        float den[CBLK], num[CBLK], cmx[CBLK];
        #pragma unroll
        for (int c = 0; c < CBLK; ++c) { den[c] = 0.f; num[c] = 0.f; cmx[c] = -3.4e38f; }

        for (int kk = 0; kk < KPT; ++kk) {
            const int k = k0 + kk;
            float xv[6];
            #pragma unroll
            for (int c = 0; c < 6; ++c) xv[c] = xb[(size_t)c * (NN * KK) + k];

            // pos_h[64]
            float ph[64];
            #pragma unroll
            for (int j = 0; j < 64; ++j) {
                float a = W[BP1_O + j]
                        + W[WP1_O + j * 3 + 0] * xv[3]
                        + W[WP1_O + j * 3 + 1] * xv[4]
                        + W[WP1_O + j * 3 + 2] * xv[5];
                ph[j] = lrelu(a);
            }
            // attn_h[16]
            float ah[16];
            #pragma unroll
            for (int j = 0; j < 16; ++j) {
                float a = W[BA1_O + j];
                #pragma unroll
                for (int i = 0; i < 6; ++i) a += W[WA1_O + j * 6 + i] * xv[i];
                ah[j] = lrelu(a);
            }
            // gate scalar
            float ga = W[GB2_O];
            #pragma unroll
            for (int j = 0; j < 16; ++j) {
                float a = W[BG1_O + j];
                #pragma unroll
                for (int i = 0; i < 6; ++i) a += W[WG1_O + j * 6 + i] * xv[i];
                ga += W[WG2_O + j] * lrelu(a);
            }
            const float gate = 1.0f / (1.0f + __expf(-ga));

            // per-channel: pos_enc, trans_feat, attn logits, online softmax/max
            #pragma unroll
            for (int c = 0; c < CBLK; ++c) {
                const int cc = c0 + c;
                float pe = W[BP2_O + cc];
                #pragma unroll
                for (int j = 0; j < 64; ++j) pe += W[WP2_O + cc * 64 + j] * ph[j];
                float tf = W[BT_O + cc];
                #pragma unroll
                for (int i = 0; i < 6; ++i) tf += W[WT_O + cc * 6 + i] * xv[i];
                tf = lrelu(tf) + pe;
                float lg = W[AB2_O + cc] + pe;
                #pragma unroll
                for (int j = 0; j < 16; ++j) lg += W[WA2_O + cc * 16 + j] * ah[j];
                const float e = __expf(lg);
                den[c] += e;
                num[c] += tf * e;
                cmx[c] = fmaxf(cmx[c], tf * gate);
            }
        }

        // combine the 4 k-slices (lanes 4t..4t+3 hold the same (b,n))
        #pragma unroll
        for (int c = 0; c < CBLK; ++c) {
            den[c] += __shfl_xor(den[c], 1);
            den[c] += __shfl_xor(den[c], 2);
            num[c] += __shfl_xor(num[c], 1);
            num[c] += __shfl_xor(num[c], 2);
            cmx[c] = fmaxf(cmx[c], __shfl_xor(cmx[c], 1));
            cmx[c] = fmaxf(cmx[c], __shfl_xor(cmx[c], 2));
        }

        // each of the 4 lanes writes 4 of the 16 channels (compile-time indices)
        #pragma unroll
        for (int c = 0; c < CBLK; ++c) {
            if ((c & 3) == ks) {
                out[((size_t)(b * 64 + c0 + c)) * NN + n] = num[c] / den[c] + cmx[c];
            }
        }
    }
}

extern "C" void kernel_launch(void* const* d_in, const int* in_sizes, int n_in,
                              void* d_out, int out_size, void* d_ws, size_t ws_size,
                              hipStream_t stream) {
    const float* x       = (const float*)d_in[0];
    const float* trans_w = (const float*)d_in[1];
    const float* trans_g = (const float*)d_in[2];
    const float* trans_b = (const float*)d_in[3];
    const float* trans_m = (const float*)d_in[4];
    const float* trans_v = (const float*)d_in[5];
    const float* pos_w1  = (const float*)d_in[6];
    const float* pos_g   = (const float*)d_in[7];
    const float* pos_b   = (const float*)d_in[8];
    const float* pos_m   = (const float*)d_in[9];
    const float* pos_v   = (const float*)d_in[10];
    const float* pos_w2  = (const float*)d_in[11];
    const float* pos_b2  = (const float*)d_in[12];
    const float* gate_w1 = (const float*)d_in[13];
    const float* gate_g  = (const float*)d_in[14];
    const float* gate_b  = (const float*)d_in[15];
    const float* gate_m  = (const float*)d_in[16];
    const float* gate_v  = (const float*)d_in[17];
    const float* gate_w2 = (const float*)d_in[18];
    const float* gate_b2 = (const float*)d_in[19];
    const float* attn_w1 = (const float*)d_in[20];
    const float* attn_g  = (const float*)d_in[21];
    const float* attn_b  = (const float*)d_in[22];
    const float* attn_m  = (const float*)d_in[23];
    const float* attn_v  = (const float*)d_in[24];
    const float* attn_w2 = (const float*)d_in[25];
    const float* attn_b2 = (const float*)d_in[26];
    float* out = (float*)d_out;

    const int total_threads = BB * NN * KSPLIT;   // 262144
    const int grid = total_threads / 256;         // 1024
    gsl_kernel<<<grid, 256, 0, stream>>>(
        x, trans_w, trans_g, trans_b, trans_m, trans_v,
        pos_w1, pos_g, pos_b, pos_m, pos_v, pos_w2, pos_b2,
        gate_w1, gate_g, gate_b, gate_m, gate_v, gate_w2, gate_b2,
        attn_w1, attn_g, attn_b, attn_m, attn_v, attn_w2, attn_b2,
        out);
}

// Round 2
// 4567.649 us; speedup vs baseline: 3.1328x; 3.1328x over previous
//
#include <hip/hip_runtime.h>
#include <math.h>

#define NEG 0.2f
#define EPSV 1e-5f

// LDS layout (float offsets, all 16B-aligned)
constexpr int PP_O   = 0;      // 64*4  pos1 packed {w0*s,w1*s,w2*s,bias}
constexpr int AP_O   = 256;    // 16*8  attn1 packed {w0..w5 (folded), bias, pad}
constexpr int GP_O   = 384;    // 16*8  gate1 packed {w0..w5 (folded), bias, gate_w2}
constexpr int W2T_O  = 512;    // 64*64 W2T[j*64+c] = pos_w2[c*64+j]
constexpr int WA2T_O = 4608;   // 16*64 WA2T[j*64+c] = attn_w2[c*16+j]
constexpr int WTT_O  = 5632;   // 6*64  WTT[i*64+c] = trans_w[c*6+i]*s
constexpr int BT_O   = 6016;   // 64 folded trans bias
constexpr int BP2_O  = 6080;   // 64 pos_b2
constexpr int AB2_O  = 6144;   // 64 attn_b2
constexpr int GB2_O  = 6208;   // 1 (+3 pad)
constexpr int WTOT   = 6212;

__device__ __forceinline__ float lrelu(float v) { return fmaxf(v, NEG * v); }

__device__ __forceinline__ float4 fma4(float4 w, float s, float4 a) {
    a.x += w.x * s; a.y += w.y * s; a.z += w.z * s; a.w += w.w * s; return a;
}
__device__ __forceinline__ float4 lrelu4(float4 v) {
    v.x = lrelu(v.x); v.y = lrelu(v.y); v.z = lrelu(v.z); v.w = lrelu(v.w); return v;
}
__device__ __forceinline__ float4 add4(float4 a, float4 b) {
    a.x += b.x; a.y += b.y; a.z += b.z; a.w += b.w; return a;
}

__global__ __launch_bounds__(256, 4)
void gsl_kernel(const float* __restrict__ x,
                const float* __restrict__ trans_w, const float* __restrict__ trans_g,
                const float* __restrict__ trans_b, const float* __restrict__ trans_m,
                const float* __restrict__ trans_v,
                const float* __restrict__ pos_w1, const float* __restrict__ pos_g,
                const float* __restrict__ pos_b, const float* __restrict__ pos_m,
                const float* __restrict__ pos_v, const float* __restrict__ pos_w2,
                const float* __restrict__ pos_b2,
                const float* __restrict__ gate_w1, const float* __restrict__ gate_g,
                const float* __restrict__ gate_b, const float* __restrict__ gate_m,
                const float* __restrict__ gate_v, const float* __restrict__ gate_w2,
                const float* __restrict__ gate_b2,
                const float* __restrict__ attn_w1, const float* __restrict__ attn_g,
                const float* __restrict__ attn_b, const float* __restrict__ attn_m,
                const float* __restrict__ attn_v, const float* __restrict__ attn_w2,
                const float* __restrict__ attn_b2,
                float* __restrict__ out)
{
    __shared__ __align__(16) float W[WTOT];
    const int tid = threadIdx.x;

    // ---- stage transposed / BN-folded weights into LDS ----
    for (int i = tid; i < 64 * 64; i += 256) {
        int c = i & 63, j = i >> 6;
        W[W2T_O + i] = pos_w2[c * 64 + j];
    }
    for (int i = tid; i < 16 * 64; i += 256) {
        int c = i & 63, j = i >> 6;
        W[WA2T_O + i] = attn_w2[c * 16 + j];
    }
    if (tid < 64) {
        int c = tid;
        float st = trans_g[c] * rsqrtf(trans_v[c] + EPSV);
        #pragma unroll
        for (int i = 0; i < 6; ++i) W[WTT_O + i * 64 + c] = trans_w[c * 6 + i] * st;
        W[BT_O + c] = trans_b[c] - trans_m[c] * st;
        float sp = pos_g[c] * rsqrtf(pos_v[c] + EPSV);
        #pragma unroll
        for (int i = 0; i < 3; ++i) W[PP_O + c * 4 + i] = pos_w1[c * 3 + i] * sp;
        W[PP_O + c * 4 + 3] = pos_b[c] - pos_m[c] * sp;
        W[BP2_O + c] = pos_b2[c];
        W[AB2_O + c] = attn_b2[c];
    } else if (tid < 80) {
        int j = tid - 64;
        float sa = attn_g[j] * rsqrtf(attn_v[j] + EPSV);
        #pragma unroll
        for (int i = 0; i < 6; ++i) W[AP_O + j * 8 + i] = attn_w1[j * 6 + i] * sa;
        W[AP_O + j * 8 + 6] = attn_b[j] - attn_m[j] * sa;
        W[AP_O + j * 8 + 7] = 0.f;
    } else if (tid < 96) {
        int j = tid - 80;
        float sg = gate_g[j] * rsqrtf(gate_v[j] + EPSV);
        #pragma unroll
        for (int i = 0; i < 6; ++i) W[GP_O + j * 8 + i] = gate_w1[j * 6 + i] * sg;
        W[GP_O + j * 8 + 6] = gate_b[j] - gate_m[j] * sg;
        W[GP_O + j * 8 + 7] = gate_w2[j];
    } else if (tid == 96) {
        W[GB2_O] = gate_b2[0];
    }
    __syncthreads();

    const float4* PPv   = (const float4*)(W + PP_O);
    const float4* APv   = (const float4*)(W + AP_O);
    const float4* GPv   = (const float4*)(W + GP_O);
    const float4* W2Tv  = (const float4*)(W + W2T_O);
    const float4* WA2Tv = (const float4*)(W + WA2T_O);
    const float4* WTTv  = (const float4*)(W + WTT_O);
    const float4* BTv   = (const float4*)(W + BT_O);
    const float4* BP2v  = (const float4*)(W + BP2_O);
    const float4* AB2v  = (const float4*)(W + AB2_O);
    const float gb2 = W[GB2_O];

    // thread = (b,n) point x k-slice (4 slices of 5)
    const int g = blockIdx.x * 256 + tid;
    const int point = g >> 2;
    const int ks = g & 3;
    const int b = point >> 13;
    const int n = point & 8191;
    const float* xb = x + ((size_t)(b * 6) * 8192 + n) * 20 + ks * 5;

    #pragma unroll 1
    for (int cb = 0; cb < 4; ++cb) {          // 16 channels per pass
        const int q0 = cb * 4;                 // float4 column base
        float4 den[4], num[4], cmx[4];
        #pragma unroll
        for (int q = 0; q < 4; ++q) {
            den[q] = make_float4(0.f, 0.f, 0.f, 0.f);
            num[q] = make_float4(0.f, 0.f, 0.f, 0.f);
            cmx[q] = make_float4(-3.4e38f, -3.4e38f, -3.4e38f, -3.4e38f);
        }

        #pragma unroll 1
        for (int kk = 0; kk < 5; ++kk) {
            float xv[6];
            #pragma unroll
            for (int i = 0; i < 6; ++i) xv[i] = xb[(size_t)i * 163840 + kk];

            // attn hidden + gate scalar (streamed, no big arrays)
            float ah[16];
            float ga = gb2;
            #pragma unroll
            for (int j = 0; j < 16; ++j) {
                float4 a0 = APv[j * 2], a1 = APv[j * 2 + 1];
                ah[j] = lrelu(a0.x * xv[0] + a0.y * xv[1] + a0.z * xv[2] +
                              a0.w * xv[3] + a1.x * xv[4] + a1.y * xv[5] + a1.z);
                float4 g0 = GPv[j * 2], g1 = GPv[j * 2 + 1];
                ga += g1.w * lrelu(g0.x * xv[0] + g0.y * xv[1] + g0.z * xv[2] +
                                   g0.w * xv[3] + g1.x * xv[4] + g1.y * xv[5] + g1.z);
            }
            const float gate = 1.f / (1.f + __expf(-ga));

            // pos_enc: stream ph_j, fuse into 16-wide accumulator
            float4 pe[4];
            #pragma unroll
            for (int q = 0; q < 4; ++q) pe[q] = BP2v[q0 + q];
            #pragma unroll 8
            for (int j = 0; j < 64; ++j) {
                float4 pw = PPv[j];
                float phj = lrelu(pw.w + pw.x * xv[3] + pw.y * xv[4] + pw.z * xv[5]);
                #pragma unroll
                for (int q = 0; q < 4; ++q)
                    pe[q] = fma4(W2Tv[j * 16 + q0 + q], phj, pe[q]);
            }

            // trans_feat
            float4 tf[4];
            #pragma unroll
            for (int q = 0; q < 4; ++q) tf[q] = BTv[q0 + q];
            #pragma unroll
            for (int i = 0; i < 6; ++i) {
                #pragma unroll
                for (int q = 0; q < 4; ++q)
                    tf[q] = fma4(WTTv[i * 16 + q0 + q], xv[i], tf[q]);
            }
            #pragma unroll
            for (int q = 0; q < 4; ++q) tf[q] = add4(lrelu4(tf[q]), pe[q]);

            // attn logits (reuse pe regs)
            #pragma unroll
            for (int q = 0; q < 4; ++q) pe[q] = add4(AB2v[q0 + q], pe[q]);
            #pragma unroll
            for (int j = 0; j < 16; ++j) {
                #pragma unroll
                for (int q = 0; q < 4; ++q)
                    pe[q] = fma4(WA2Tv[j * 16 + q0 + q], ah[j], pe[q]);
            }

            // online accumulate
            #pragma unroll
            for (int q = 0; q < 4; ++q) {
                float4 e;
                e.x = __expf(pe[q].x); e.y = __expf(pe[q].y);
                e.z = __expf(pe[q].z); e.w = __expf(pe[q].w);
                den[q] = add4(den[q], e);
                num[q].x += tf[q].x * e.x; num[q].y += tf[q].y * e.y;
                num[q].z += tf[q].z * e.z; num[q].w += tf[q].w * e.w;
                cmx[q].x = fmaxf(cmx[q].x, tf[q].x * gate);
                cmx[q].y = fmaxf(cmx[q].y, tf[q].y * gate);
                cmx[q].z = fmaxf(cmx[q].z, tf[q].z * gate);
                cmx[q].w = fmaxf(cmx[q].w, tf[q].w * gate);
            }
        }

        // combine the 4 k-slices (lanes 4t..4t+3 share one (b,n))
        #pragma unroll
        for (int q = 0; q < 4; ++q) {
            float4 d = den[q], u = num[q], m = cmx[q];
            d.x += __shfl_xor(d.x, 1); d.x += __shfl_xor(d.x, 2);
            d.y += __shfl_xor(d.y, 1); d.y += __shfl_xor(d.y, 2);
            d.z += __shfl_xor(d.z, 1); d.z += __shfl_xor(d.z, 2);
            d.w += __shfl_xor(d.w, 1); d.w += __shfl_xor(d.w, 2);
            u.x += __shfl_xor(u.x, 1); u.x += __shfl_xor(u.x, 2);
            u.y += __shfl_xor(u.y, 1); u.y += __shfl_xor(u.y, 2);
            u.z += __shfl_xor(u.z, 1); u.z += __shfl_xor(u.z, 2);
            u.w += __shfl_xor(u.w, 1); u.w += __shfl_xor(u.w, 2);
            m.x = fmaxf(m.x, __shfl_xor(m.x, 1)); m.x = fmaxf(m.x, __shfl_xor(m.x, 2));
            m.y = fmaxf(m.y, __shfl_xor(m.y, 1)); m.y = fmaxf(m.y, __shfl_xor(m.y, 2));
            m.z = fmaxf(m.z, __shfl_xor(m.z, 1)); m.z = fmaxf(m.z, __shfl_xor(m.z, 2));
            m.w = fmaxf(m.w, __shfl_xor(m.w, 1)); m.w = fmaxf(m.w, __shfl_xor(m.w, 2));

            // channel c = cb*16 + q*4 + r; component r is written by lane with ks==r
            const size_t ob = ((size_t)(b * 64 + cb * 16 + q * 4)) * 8192 + n;
            if (ks == 0) out[ob]            = u.x / d.x + m.x;
            if (ks == 1) out[ob + 8192]     = u.y / d.y + m.y;
            if (ks == 2) out[ob + 16384]    = u.z / d.z + m.z;
            if (ks == 3) out[ob + 24576]    = u.w / d.w + m.w;
        }
    }
}

extern "C" void kernel_launch(void* const* d_in, const int* in_sizes, int n_in,
                              void* d_out, int out_size, void* d_ws, size_t ws_size,
                              hipStream_t stream) {
    const float* x       = (const float*)d_in[0];
    const float* trans_w = (const float*)d_in[1];
    const float* trans_g = (const float*)d_in[2];
    const float* trans_b = (const float*)d_in[3];
    const float* trans_m = (const float*)d_in[4];
    const float* trans_v = (const float*)d_in[5];
    const float* pos_w1  = (const float*)d_in[6];
    const float* pos_g   = (const float*)d_in[7];
    const float* pos_b   = (const float*)d_in[8];
    const float* pos_m   = (const float*)d_in[9];
    const float* pos_v   = (const float*)d_in[10];
    const float* pos_w2  = (const float*)d_in[11];
    const float* pos_b2  = (const float*)d_in[12];
    const float* gate_w1 = (const float*)d_in[13];
    const float* gate_g  = (const float*)d_in[14];
    const float* gate_b  = (const float*)d_in[15];
    const float* gate_m  = (const float*)d_in[16];
    const float* gate_v  = (const float*)d_in[17];
    const float* gate_w2 = (const float*)d_in[18];
    const float* gate_b2 = (const float*)d_in[19];
    const float* attn_w1 = (const float*)d_in[20];
    const float* attn_g  = (const float*)d_in[21];
    const float* attn_b  = (const float*)d_in[22];
    const float* attn_m  = (const float*)d_in[23];
    const float* attn_v  = (const float*)d_in[24];
    const float* attn_w2 = (const float*)d_in[25];
    const float* attn_b2 = (const float*)d_in[26];
    float* out = (float*)d_out;

    const int total_threads = 8 * 8192 * 4;   // 262144
    const int grid = total_threads / 256;     // 1024 blocks
    gsl_kernel<<<grid, 256, 0, stream>>>(
        x, trans_w, trans_g, trans_b, trans_m, trans_v,
        pos_w1, pos_g, pos_b, pos_m, pos_v, pos_w2, pos_b2,
        gate_w1, gate_g, gate_b, gate_m, gate_v, gate_w2, gate_b2,
        attn_w1, attn_g, attn_b, attn_m, attn_v, attn_w2, attn_b2,
        out);
}

// Round 3
// 4556.853 us; speedup vs baseline: 3.1402x; 1.0024x over previous
//
#include <hip/hip_runtime.h>
#include <math.h>

#define NEG 0.2f
#define EPSV 1e-5f

// LDS layout (float offsets, all 16B-aligned)
constexpr int PP_O   = 0;      // 64*4  pos1 packed {w0*s,w1*s,w2*s,bias}
constexpr int AP_O   = 256;    // 16*8  attn1 packed {w0..w5 (folded), bias, pad}
constexpr int GP_O   = 384;    // 16*8  gate1 packed {w0..w5 (folded), bias, gate_w2}
constexpr int W2T_O  = 512;    // 64*64 W2T[j*64+c] = pos_w2[c*64+j]
constexpr int WA2T_O = 4608;   // 16*64 WA2T[j*64+c] = attn_w2[c*16+j]
constexpr int WTT_O  = 5632;   // 6*64  WTT[i*64+c] = trans_w[c*6+i]*s
constexpr int BT_O   = 6016;   // 64 folded trans bias
constexpr int BP2_O  = 6080;   // 64 pos_b2
constexpr int AB2_O  = 6144;   // 64 attn_b2
constexpr int GB2_O  = 6208;   // 1 (+3 pad)
constexpr int WTOT   = 6212;

__device__ __forceinline__ float lrelu(float v) { return fmaxf(v, NEG * v); }

__device__ __forceinline__ float4 fma4(float4 w, float s, float4 a) {
    a.x += w.x * s; a.y += w.y * s; a.z += w.z * s; a.w += w.w * s; return a;
}
__device__ __forceinline__ float4 lrelu4(float4 v) {
    v.x = lrelu(v.x); v.y = lrelu(v.y); v.z = lrelu(v.z); v.w = lrelu(v.w); return v;
}
__device__ __forceinline__ float4 add4(float4 a, float4 b) {
    a.x += b.x; a.y += b.y; a.z += b.z; a.w += b.w; return a;
}

// waves_per_eu(4,4): pin register budget to 128 VGPR. Round 2 showed LLVM
// targeting 8 waves/EU (64 VGPR) and spilling the softmax accumulators to
// scratch every kk iteration (3.8 GB of WRITE_SIZE). Live state here is ~112.
__global__ __launch_bounds__(256) __attribute__((amdgpu_waves_per_eu(4, 4)))
void gsl_kernel(const float* __restrict__ x,
                const float* __restrict__ trans_w, const float* __restrict__ trans_g,
                const float* __restrict__ trans_b, const float* __restrict__ trans_m,
                const float* __restrict__ trans_v,
                const float* __restrict__ pos_w1, const float* __restrict__ pos_g,
                const float* __restrict__ pos_b, const float* __restrict__ pos_m,
                const float* __restrict__ pos_v, const float* __restrict__ pos_w2,
                const float* __restrict__ pos_b2,
                const float* __restrict__ gate_w1, const float* __restrict__ gate_g,
                const float* __restrict__ gate_b, const float* __restrict__ gate_m,
                const float* __restrict__ gate_v, const float* __restrict__ gate_w2,
                const float* __restrict__ gate_b2,
                const float* __restrict__ attn_w1, const float* __restrict__ attn_g,
                const float* __restrict__ attn_b, const float* __restrict__ attn_m,
                const float* __restrict__ attn_v, const float* __restrict__ attn_w2,
                const float* __restrict__ attn_b2,
                float* __restrict__ out)
{
    __shared__ __align__(16) float W[WTOT];
    const int tid = threadIdx.x;

    // ---- stage transposed / BN-folded weights into LDS ----
    for (int i = tid; i < 64 * 64; i += 256) {
        int c = i & 63, j = i >> 6;
        W[W2T_O + i] = pos_w2[c * 64 + j];
    }
    for (int i = tid; i < 16 * 64; i += 256) {
        int c = i & 63, j = i >> 6;
        W[WA2T_O + i] = attn_w2[c * 16 + j];
    }
    if (tid < 64) {
        int c = tid;
        float st = trans_g[c] * rsqrtf(trans_v[c] + EPSV);
        #pragma unroll
        for (int i = 0; i < 6; ++i) W[WTT_O + i * 64 + c] = trans_w[c * 6 + i] * st;
        W[BT_O + c] = trans_b[c] - trans_m[c] * st;
        float sp = pos_g[c] * rsqrtf(pos_v[c] + EPSV);
        #pragma unroll
        for (int i = 0; i < 3; ++i) W[PP_O + c * 4 + i] = pos_w1[c * 3 + i] * sp;
        W[PP_O + c * 4 + 3] = pos_b[c] - pos_m[c] * sp;
        W[BP2_O + c] = pos_b2[c];
        W[AB2_O + c] = attn_b2[c];
    } else if (tid < 80) {
        int j = tid - 64;
        float sa = attn_g[j] * rsqrtf(attn_v[j] + EPSV);
        #pragma unroll
        for (int i = 0; i < 6; ++i) W[AP_O + j * 8 + i] = attn_w1[j * 6 + i] * sa;
        W[AP_O + j * 8 + 6] = attn_b[j] - attn_m[j] * sa;
        W[AP_O + j * 8 + 7] = 0.f;
    } else if (tid < 96) {
        int j = tid - 80;
        float sg = gate_g[j] * rsqrtf(gate_v[j] + EPSV);
        #pragma unroll
        for (int i = 0; i < 6; ++i) W[GP_O + j * 8 + i] = gate_w1[j * 6 + i] * sg;
        W[GP_O + j * 8 + 6] = gate_b[j] - gate_m[j] * sg;
        W[GP_O + j * 8 + 7] = gate_w2[j];
    } else if (tid == 96) {
        W[GB2_O] = gate_b2[0];
    }
    __syncthreads();

    const float4* PPv   = (const float4*)(W + PP_O);
    const float4* APv   = (const float4*)(W + AP_O);
    const float4* GPv   = (const float4*)(W + GP_O);
    const float4* W2Tv  = (const float4*)(W + W2T_O);
    const float4* WA2Tv = (const float4*)(W + WA2T_O);
    const float4* WTTv  = (const float4*)(W + WTT_O);
    const float4* BTv   = (const float4*)(W + BT_O);
    const float4* BP2v  = (const float4*)(W + BP2_O);
    const float4* AB2v  = (const float4*)(W + AB2_O);
    const float gb2 = W[GB2_O];

    // thread = (b,n) point x k-slice (4 slices of 5)
    const int g = blockIdx.x * 256 + tid;
    const int point = g >> 2;
    const int ks = g & 3;
    const int b = point >> 13;
    const int n = point & 8191;
    const float* xb = x + ((size_t)(b * 6) * 8192 + n) * 20 + ks * 5;

    #pragma unroll 1
    for (int cb = 0; cb < 4; ++cb) {          // 16 channels per pass
        const int q0 = cb * 4;                 // float4 column base
        float4 den[4], num[4], cmx[4];
        #pragma unroll
        for (int q = 0; q < 4; ++q) {
            den[q] = make_float4(0.f, 0.f, 0.f, 0.f);
            num[q] = make_float4(0.f, 0.f, 0.f, 0.f);
            cmx[q] = make_float4(-3.4e38f, -3.4e38f, -3.4e38f, -3.4e38f);
        }

        #pragma unroll 1
        for (int kk = 0; kk < 5; ++kk) {
            float xv[6];
            #pragma unroll
            for (int i = 0; i < 6; ++i) xv[i] = xb[(size_t)i * 163840 + kk];

            // attn hidden + gate scalar (streamed, no big arrays)
            float ah[16];
            float ga = gb2;
            #pragma unroll
            for (int j = 0; j < 16; ++j) {
                float4 a0 = APv[j * 2], a1 = APv[j * 2 + 1];
                ah[j] = lrelu(a0.x * xv[0] + a0.y * xv[1] + a0.z * xv[2] +
                              a0.w * xv[3] + a1.x * xv[4] + a1.y * xv[5] + a1.z);
                float4 g0 = GPv[j * 2], g1 = GPv[j * 2 + 1];
                ga += g1.w * lrelu(g0.x * xv[0] + g0.y * xv[1] + g0.z * xv[2] +
                                   g0.w * xv[3] + g1.x * xv[4] + g1.y * xv[5] + g1.z);
            }
            const float gate = 1.f / (1.f + __expf(-ga));

            // pos_enc: stream ph_j, fuse into 16-wide accumulator
            float4 pe[4];
            #pragma unroll
            for (int q = 0; q < 4; ++q) pe[q] = BP2v[q0 + q];
            #pragma unroll 8
            for (int j = 0; j < 64; ++j) {
                float4 pw = PPv[j];
                float phj = lrelu(pw.w + pw.x * xv[3] + pw.y * xv[4] + pw.z * xv[5]);
                #pragma unroll
                for (int q = 0; q < 4; ++q)
                    pe[q] = fma4(W2Tv[j * 16 + q0 + q], phj, pe[q]);
            }

            // trans_feat
            float4 tf[4];
            #pragma unroll
            for (int q = 0; q < 4; ++q) tf[q] = BTv[q0 + q];
            #pragma unroll
            for (int i = 0; i < 6; ++i) {
                #pragma unroll
                for (int q = 0; q < 4; ++q)
                    tf[q] = fma4(WTTv[i * 16 + q0 + q], xv[i], tf[q]);
            }
            #pragma unroll
            for (int q = 0; q < 4; ++q) tf[q] = add4(lrelu4(tf[q]), pe[q]);

            // attn logits (reuse pe regs)
            #pragma unroll
            for (int q = 0; q < 4; ++q) pe[q] = add4(AB2v[q0 + q], pe[q]);
            #pragma unroll
            for (int j = 0; j < 16; ++j) {
                #pragma unroll
                for (int q = 0; q < 4; ++q)
                    pe[q] = fma4(WA2Tv[j * 16 + q0 + q], ah[j], pe[q]);
            }

            // online accumulate
            #pragma unroll
            for (int q = 0; q < 4; ++q) {
                float4 e;
                e.x = __expf(pe[q].x); e.y = __expf(pe[q].y);
                e.z = __expf(pe[q].z); e.w = __expf(pe[q].w);
                den[q] = add4(den[q], e);
                num[q].x += tf[q].x * e.x; num[q].y += tf[q].y * e.y;
                num[q].z += tf[q].z * e.z; num[q].w += tf[q].w * e.w;
                cmx[q].x = fmaxf(cmx[q].x, tf[q].x * gate);
                cmx[q].y = fmaxf(cmx[q].y, tf[q].y * gate);
                cmx[q].z = fmaxf(cmx[q].z, tf[q].z * gate);
                cmx[q].w = fmaxf(cmx[q].w, tf[q].w * gate);
            }
        }

        // combine the 4 k-slices (lanes 4t..4t+3 share one (b,n))
        #pragma unroll
        for (int q = 0; q < 4; ++q) {
            float4 d = den[q], u = num[q], m = cmx[q];
            d.x += __shfl_xor(d.x, 1); d.x += __shfl_xor(d.x, 2);
            d.y += __shfl_xor(d.y, 1); d.y += __shfl_xor(d.y, 2);
            d.z += __shfl_xor(d.z, 1); d.z += __shfl_xor(d.z, 2);
            d.w += __shfl_xor(d.w, 1); d.w += __shfl_xor(d.w, 2);
            u.x += __shfl_xor(u.x, 1); u.x += __shfl_xor(u.x, 2);
            u.y += __shfl_xor(u.y, 1); u.y += __shfl_xor(u.y, 2);
            u.z += __shfl_xor(u.z, 1); u.z += __shfl_xor(u.z, 2);
            u.w += __shfl_xor(u.w, 1); u.w += __shfl_xor(u.w, 2);
            m.x = fmaxf(m.x, __shfl_xor(m.x, 1)); m.x = fmaxf(m.x, __shfl_xor(m.x, 2));
            m.y = fmaxf(m.y, __shfl_xor(m.y, 1)); m.y = fmaxf(m.y, __shfl_xor(m.y, 2));
            m.z = fmaxf(m.z, __shfl_xor(m.z, 1)); m.z = fmaxf(m.z, __shfl_xor(m.z, 2));
            m.w = fmaxf(m.w, __shfl_xor(m.w, 1)); m.w = fmaxf(m.w, __shfl_xor(m.w, 2));

            // channel c = cb*16 + q*4 + r; component r is written by lane with ks==r
            const size_t ob = ((size_t)(b * 64 + cb * 16 + q * 4)) * 8192 + n;
            if (ks == 0) out[ob]            = u.x / d.x + m.x;
            if (ks == 1) out[ob + 8192]     = u.y / d.y + m.y;
            if (ks == 2) out[ob + 16384]    = u.z / d.z + m.z;
            if (ks == 3) out[ob + 24576]    = u.w / d.w + m.w;
        }
    }
}

extern "C" void kernel_launch(void* const* d_in, const int* in_sizes, int n_in,
                              void* d_out, int out_size, void* d_ws, size_t ws_size,
                              hipStream_t stream) {
    const float* x       = (const float*)d_in[0];
    const float* trans_w = (const float*)d_in[1];
    const float* trans_g = (const float*)d_in[2];
    const float* trans_b = (const float*)d_in[3];
    const float* trans_m = (const float*)d_in[4];
    const float* trans_v = (const float*)d_in[5];
    const float* pos_w1  = (const float*)d_in[6];
    const float* pos_g   = (const float*)d_in[7];
    const float* pos_b   = (const float*)d_in[8];
    const float* pos_m   = (const float*)d_in[9];
    const float* pos_v   = (const float*)d_in[10];
    const float* pos_w2  = (const float*)d_in[11];
    const float* pos_b2  = (const float*)d_in[12];
    const float* gate_w1 = (const float*)d_in[13];
    const float* gate_g  = (const float*)d_in[14];
    const float* gate_b  = (const float*)d_in[15];
    const float* gate_m  = (const float*)d_in[16];
    const float* gate_v  = (const float*)d_in[17];
    const float* gate_w2 = (const float*)d_in[18];
    const float* gate_b2 = (const float*)d_in[19];
    const float* attn_w1 = (const float*)d_in[20];
    const float* attn_g  = (const float*)d_in[21];
    const float* attn_b  = (const float*)d_in[22];
    const float* attn_m  = (const float*)d_in[23];
    const float* attn_v  = (const float*)d_in[24];
    const float* attn_w2 = (const float*)d_in[25];
    const float* attn_b2 = (const float*)d_in[26];
    float* out = (float*)d_out;

    const int total_threads = 8 * 8192 * 4;   // 262144
    const int grid = total_threads / 256;     // 1024 blocks
    gsl_kernel<<<grid, 256, 0, stream>>>(
        x, trans_w, trans_g, trans_b, trans_m, trans_v,
        pos_w1, pos_g, pos_b, pos_m, pos_v, pos_w2, pos_b2,
        gate_w1, gate_g, gate_b, gate_m, gate_v, gate_w2, gate_b2,
        attn_w1, attn_g, attn_b, attn_m, attn_v, attn_w2, attn_b2,
        out);
}

// Round 4
// 3516.972 us; speedup vs baseline: 4.0687x; 1.2957x over previous
//
#include <hip/hip_runtime.h>
#include <math.h>

#define NEG 0.2f
#define EPSV 1e-5f

// LDS layout (float offsets, all 16B-aligned)
constexpr int PP_O   = 0;      // 64*4  pos1 packed {w0*s,w1*s,w2*s,bias}
constexpr int AP_O   = 256;    // 16*8  attn1 packed {w0..w5 (folded), bias, pad}
constexpr int GP_O   = 384;    // 16*8  gate1 packed {w0..w5 (folded), bias, gate_w2}
constexpr int W2T_O  = 512;    // 64*64 W2T[j*64+c] = pos_w2[c*64+j]
constexpr int WA2T_O = 4608;   // 16*64 WA2T[j*64+c] = attn_w2[c*16+j]
constexpr int WTT_O  = 5632;   // 6*64  WTT[i*64+c] = trans_w[c*6+i]*s
constexpr int BT_O   = 6016;   // 64 folded trans bias
constexpr int BP2_O  = 6080;   // 64 pos_b2
constexpr int AB2_O  = 6144;   // 64 attn_b2
constexpr int GB2_O  = 6208;   // 1 (+3 pad)
constexpr int WTOT   = 6212;

__device__ __forceinline__ float lrelu(float v) { return fmaxf(v, NEG * v); }

__device__ __forceinline__ float4 fma4(float4 w, float s, float4 a) {
    a.x += w.x * s; a.y += w.y * s; a.z += w.z * s; a.w += w.w * s; return a;
}
__device__ __forceinline__ float4 lrelu4(float4 v) {
    v.x = lrelu(v.x); v.y = lrelu(v.y); v.z = lrelu(v.z); v.w = lrelu(v.w); return v;
}
__device__ __forceinline__ float4 add4(float4 a, float4 b) {
    a.x += b.x; a.y += b.y; a.z += b.z; a.w += b.w; return a;
}

// __launch_bounds__(256, 2): empirically (round 1) this yields a 128-VGPR
// budget on this toolchain; min-waves=4 variants (rounds 2/3) yielded 64 VGPRs
// and spilled the ~112-reg live state to scratch (3.8 GB WRITE_SIZE). Live
// state here fits 128.
__global__ __launch_bounds__(256, 2)
void gsl_kernel(const float* __restrict__ x,
                const float* __restrict__ trans_w, const float* __restrict__ trans_g,
                const float* __restrict__ trans_b, const float* __restrict__ trans_m,
                const float* __restrict__ trans_v,
                const float* __restrict__ pos_w1, const float* __restrict__ pos_g,
                const float* __restrict__ pos_b, const float* __restrict__ pos_m,
                const float* __restrict__ pos_v, const float* __restrict__ pos_w2,
                const float* __restrict__ pos_b2,
                const float* __restrict__ gate_w1, const float* __restrict__ gate_g,
                const float* __restrict__ gate_b, const float* __restrict__ gate_m,
                const float* __restrict__ gate_v, const float* __restrict__ gate_w2,
                const float* __restrict__ gate_b2,
                const float* __restrict__ attn_w1, const float* __restrict__ attn_g,
                const float* __restrict__ attn_b, const float* __restrict__ attn_m,
                const float* __restrict__ attn_v, const float* __restrict__ attn_w2,
                const float* __restrict__ attn_b2,
                float* __restrict__ out)
{
    __shared__ __align__(16) float W[WTOT];
    const int tid = threadIdx.x;

    // ---- stage transposed / BN-folded weights into LDS ----
    for (int i = tid; i < 64 * 64; i += 256) {
        int c = i & 63, j = i >> 6;
        W[W2T_O + i] = pos_w2[c * 64 + j];
    }
    for (int i = tid; i < 16 * 64; i += 256) {
        int c = i & 63, j = i >> 6;
        W[WA2T_O + i] = attn_w2[c * 16 + j];
    }
    if (tid < 64) {
        int c = tid;
        float st = trans_g[c] * rsqrtf(trans_v[c] + EPSV);
        #pragma unroll
        for (int i = 0; i < 6; ++i) W[WTT_O + i * 64 + c] = trans_w[c * 6 + i] * st;
        W[BT_O + c] = trans_b[c] - trans_m[c] * st;
        float sp = pos_g[c] * rsqrtf(pos_v[c] + EPSV);
        #pragma unroll
        for (int i = 0; i < 3; ++i) W[PP_O + c * 4 + i] = pos_w1[c * 3 + i] * sp;
        W[PP_O + c * 4 + 3] = pos_b[c] - pos_m[c] * sp;
        W[BP2_O + c] = pos_b2[c];
        W[AB2_O + c] = attn_b2[c];
    } else if (tid < 80) {
        int j = tid - 64;
        float sa = attn_g[j] * rsqrtf(attn_v[j] + EPSV);
        #pragma unroll
        for (int i = 0; i < 6; ++i) W[AP_O + j * 8 + i] = attn_w1[j * 6 + i] * sa;
        W[AP_O + j * 8 + 6] = attn_b[j] - attn_m[j] * sa;
        W[AP_O + j * 8 + 7] = 0.f;
    } else if (tid < 96) {
        int j = tid - 80;
        float sg = gate_g[j] * rsqrtf(gate_v[j] + EPSV);
        #pragma unroll
        for (int i = 0; i < 6; ++i) W[GP_O + j * 8 + i] = gate_w1[j * 6 + i] * sg;
        W[GP_O + j * 8 + 6] = gate_b[j] - gate_m[j] * sg;
        W[GP_O + j * 8 + 7] = gate_w2[j];
    } else if (tid == 96) {
        W[GB2_O] = gate_b2[0];
    }
    __syncthreads();

    const float4* PPv   = (const float4*)(W + PP_O);
    const float4* APv   = (const float4*)(W + AP_O);
    const float4* GPv   = (const float4*)(W + GP_O);
    const float4* W2Tv  = (const float4*)(W + W2T_O);
    const float4* WA2Tv = (const float4*)(W + WA2T_O);
    const float4* WTTv  = (const float4*)(W + WTT_O);
    const float4* BTv   = (const float4*)(W + BT_O);
    const float4* BP2v  = (const float4*)(W + BP2_O);
    const float4* AB2v  = (const float4*)(W + AB2_O);
    const float gb2 = W[GB2_O];

    // thread = (b,n) point x k-slice (4 slices of 5)
    const int g = blockIdx.x * 256 + tid;
    const int point = g >> 2;
    const int ks = g & 3;
    const int b = point >> 13;
    const int n = point & 8191;
    const float* xb = x + ((size_t)(b * 6) * 8192 + n) * 20 + ks * 5;

    #pragma unroll 1
    for (int cb = 0; cb < 4; ++cb) {          // 16 channels per pass
        const int q0 = cb * 4;                 // float4 column base
        float4 den[4], num[4], cmx[4];
        #pragma unroll
        for (int q = 0; q < 4; ++q) {
            den[q] = make_float4(0.f, 0.f, 0.f, 0.f);
            num[q] = make_float4(0.f, 0.f, 0.f, 0.f);
            cmx[q] = make_float4(-3.4e38f, -3.4e38f, -3.4e38f, -3.4e38f);
        }

        #pragma unroll 1
        for (int kk = 0; kk < 5; ++kk) {
            float xv[6];
            #pragma unroll
            for (int i = 0; i < 6; ++i) xv[i] = xb[(size_t)i * 163840 + kk];

            // attn hidden + gate scalar (streamed, no big arrays)
            float ah[16];
            float ga = gb2;
            #pragma unroll
            for (int j = 0; j < 16; ++j) {
                float4 a0 = APv[j * 2], a1 = APv[j * 2 + 1];
                ah[j] = lrelu(a0.x * xv[0] + a0.y * xv[1] + a0.z * xv[2] +
                              a0.w * xv[3] + a1.x * xv[4] + a1.y * xv[5] + a1.z);
                float4 g0 = GPv[j * 2], g1 = GPv[j * 2 + 1];
                ga += g1.w * lrelu(g0.x * xv[0] + g0.y * xv[1] + g0.z * xv[2] +
                                   g0.w * xv[3] + g1.x * xv[4] + g1.y * xv[5] + g1.z);
            }
            const float gate = 1.f / (1.f + __expf(-ga));

            // pos_enc: stream ph_j, fuse into 16-wide accumulator
            float4 pe[4];
            #pragma unroll
            for (int q = 0; q < 4; ++q) pe[q] = BP2v[q0 + q];
            #pragma unroll 8
            for (int j = 0; j < 64; ++j) {
                float4 pw = PPv[j];
                float phj = lrelu(pw.w + pw.x * xv[3] + pw.y * xv[4] + pw.z * xv[5]);
                #pragma unroll
                for (int q = 0; q < 4; ++q)
                    pe[q] = fma4(W2Tv[j * 16 + q0 + q], phj, pe[q]);
            }

            // trans_feat
            float4 tf[4];
            #pragma unroll
            for (int q = 0; q < 4; ++q) tf[q] = BTv[q0 + q];
            #pragma unroll
            for (int i = 0; i < 6; ++i) {
                #pragma unroll
                for (int q = 0; q < 4; ++q)
                    tf[q] = fma4(WTTv[i * 16 + q0 + q], xv[i], tf[q]);
            }
            #pragma unroll
            for (int q = 0; q < 4; ++q) tf[q] = add4(lrelu4(tf[q]), pe[q]);

            // attn logits (reuse pe regs)
            #pragma unroll
            for (int q = 0; q < 4; ++q) pe[q] = add4(AB2v[q0 + q], pe[q]);
            #pragma unroll
            for (int j = 0; j < 16; ++j) {
                #pragma unroll
                for (int q = 0; q < 4; ++q)
                    pe[q] = fma4(WA2Tv[j * 16 + q0 + q], ah[j], pe[q]);
            }

            // online accumulate
            #pragma unroll
            for (int q = 0; q < 4; ++q) {
                float4 e;
                e.x = __expf(pe[q].x); e.y = __expf(pe[q].y);
                e.z = __expf(pe[q].z); e.w = __expf(pe[q].w);
                den[q] = add4(den[q], e);
                num[q].x += tf[q].x * e.x; num[q].y += tf[q].y * e.y;
                num[q].z += tf[q].z * e.z; num[q].w += tf[q].w * e.w;
                cmx[q].x = fmaxf(cmx[q].x, tf[q].x * gate);
                cmx[q].y = fmaxf(cmx[q].y, tf[q].y * gate);
                cmx[q].z = fmaxf(cmx[q].z, tf[q].z * gate);
                cmx[q].w = fmaxf(cmx[q].w, tf[q].w * gate);
            }
        }

        // combine the 4 k-slices (lanes 4t..4t+3 share one (b,n))
        #pragma unroll
        for (int q = 0; q < 4; ++q) {
            float4 d = den[q], u = num[q], m = cmx[q];
            d.x += __shfl_xor(d.x, 1); d.x += __shfl_xor(d.x, 2);
            d.y += __shfl_xor(d.y, 1); d.y += __shfl_xor(d.y, 2);
            d.z += __shfl_xor(d.z, 1); d.z += __shfl_xor(d.z, 2);
            d.w += __shfl_xor(d.w, 1); d.w += __shfl_xor(d.w, 2);
            u.x += __shfl_xor(u.x, 1); u.x += __shfl_xor(u.x, 2);
            u.y += __shfl_xor(u.y, 1); u.y += __shfl_xor(u.y, 2);
            u.z += __shfl_xor(u.z, 1); u.z += __shfl_xor(u.z, 2);
            u.w += __shfl_xor(u.w, 1); u.w += __shfl_xor(u.w, 2);
            m.x = fmaxf(m.x, __shfl_xor(m.x, 1)); m.x = fmaxf(m.x, __shfl_xor(m.x, 2));
            m.y = fmaxf(m.y, __shfl_xor(m.y, 1)); m.y = fmaxf(m.y, __shfl_xor(m.y, 2));
            m.z = fmaxf(m.z, __shfl_xor(m.z, 1)); m.z = fmaxf(m.z, __shfl_xor(m.z, 2));
            m.w = fmaxf(m.w, __shfl_xor(m.w, 1)); m.w = fmaxf(m.w, __shfl_xor(m.w, 2));

            // channel c = cb*16 + q*4 + r; component r is written by lane with ks==r
            const size_t ob = ((size_t)(b * 64 + cb * 16 + q * 4)) * 8192 + n;
            if (ks == 0) out[ob]            = u.x / d.x + m.x;
            if (ks == 1) out[ob + 8192]     = u.y / d.y + m.y;
            if (ks == 2) out[ob + 16384]    = u.z / d.z + m.z;
            if (ks == 3) out[ob + 24576]    = u.w / d.w + m.w;
        }
    }
}

extern "C" void kernel_launch(void* const* d_in, const int* in_sizes, int n_in,
                              void* d_out, int out_size, void* d_ws, size_t ws_size,
                              hipStream_t stream) {
    const float* x       = (const float*)d_in[0];
    const float* trans_w = (const float*)d_in[1];
    const float* trans_g = (const float*)d_in[2];
    const float* trans_b = (const float*)d_in[3];
    const float* trans_m = (const float*)d_in[4];
    const float* trans_v = (const float*)d_in[5];
    const float* pos_w1  = (const float*)d_in[6];
    const float* pos_g   = (const float*)d_in[7];
    const float* pos_b   = (const float*)d_in[8];
    const float* pos_m   = (const float*)d_in[9];
    const float* pos_v   = (const float*)d_in[10];
    const float* pos_w2  = (const float*)d_in[11];
    const float* pos_b2  = (const float*)d_in[12];
    const float* gate_w1 = (const float*)d_in[13];
    const float* gate_g  = (const float*)d_in[14];
    const float* gate_b  = (const float*)d_in[15];
    const float* gate_m  = (const float*)d_in[16];
    const float* gate_v  = (const float*)d_in[17];
    const float* gate_w2 = (const float*)d_in[18];
    const float* gate_b2 = (const float*)d_in[19];
    const float* attn_w1 = (const float*)d_in[20];
    const float* attn_g  = (const float*)d_in[21];
    const float* attn_b  = (const float*)d_in[22];
    const float* attn_m  = (const float*)d_in[23];
    const float* attn_v  = (const float*)d_in[24];
    const float* attn_w2 = (const float*)d_in[25];
    const float* attn_b2 = (const float*)d_in[26];
    float* out = (float*)d_out;

    const int total_threads = 8 * 8192 * 4;   // 262144
    const int grid = total_threads / 256;     // 1024 blocks
    gsl_kernel<<<grid, 256, 0, stream>>>(
        x, trans_w, trans_g, trans_b, trans_m, trans_v,
        pos_w1, pos_g, pos_b, pos_m, pos_v, pos_w2, pos_b2,
        gate_w1, gate_g, gate_b, gate_m, gate_v, gate_w2, gate_b2,
        attn_w1, attn_g, attn_b, attn_m, attn_v, attn_w2, attn_b2,
        out);
}

// Round 5
// 708.478 us; speedup vs baseline: 20.1977x; 4.9641x over previous
//
#include <hip/hip_runtime.h>
#include <math.h>

#define NEG 0.2f
#define EPSV 1e-5f

// LDS layout (float offsets, all 16B-aligned)
constexpr int PP_O   = 0;      // 64*4  pos1 packed {w0*s,w1*s,w2*s,bias}
constexpr int AP_O   = 256;    // 16*8  attn1 packed {w0..w5 (folded), bias, pad}
constexpr int GP_O   = 384;    // 16*8  gate1 packed {w0..w5 (folded), bias, gate_w2}
constexpr int W2T_O  = 512;    // 64*64 W2T[j*64+c] = pos_w2[c*64+j]
constexpr int WA2T_O = 4608;   // 16*64 WA2T[j*64+c] = attn_w2[c*16+j]
constexpr int WTT_O  = 5632;   // 6*64  WTT[i*64+c] = trans_w[c*6+i]*s
constexpr int BT_O   = 6016;   // 64 folded trans bias
constexpr int BP2_O  = 6080;   // 64 pos_b2
constexpr int AB2_O  = 6144;   // 64 attn_b2
constexpr int GB2_O  = 6208;   // 1 (+3 pad)
constexpr int WTOT   = 6212;

__device__ __forceinline__ float lrelu(float v) { return fmaxf(v, NEG * v); }

__device__ __forceinline__ float4 fma4(float4 w, float s, float4 a) {
    a.x += w.x * s; a.y += w.y * s; a.z += w.z * s; a.w += w.w * s; return a;
}
__device__ __forceinline__ float4 lrelu4(float4 v) {
    v.x = lrelu(v.x); v.y = lrelu(v.y); v.z = lrelu(v.z); v.w = lrelu(v.w); return v;
}
__device__ __forceinline__ float4 add4(float4 a, float4 b) {
    a.x += b.x; a.y += b.y; a.z += b.z; a.w += b.w; return a;
}

// __launch_bounds__(256,2): 128-VGPR budget (evidenced round 1/4).
// Body is ordered so peak live state stays ~105 regs: pe-stream (no ah live),
// then tf, then ah/gate STREAMED into logits (ah[16] never materialized).
// Round 4 spilled because ah[16]+pe+tf+accs+temps peaked ~140 > 128.
__global__ __launch_bounds__(256, 2)
void gsl_kernel(const float* __restrict__ x,
                const float* __restrict__ trans_w, const float* __restrict__ trans_g,
                const float* __restrict__ trans_b, const float* __restrict__ trans_m,
                const float* __restrict__ trans_v,
                const float* __restrict__ pos_w1, const float* __restrict__ pos_g,
                const float* __restrict__ pos_b, const float* __restrict__ pos_m,
                const float* __restrict__ pos_v, const float* __restrict__ pos_w2,
                const float* __restrict__ pos_b2,
                const float* __restrict__ gate_w1, const float* __restrict__ gate_g,
                const float* __restrict__ gate_b, const float* __restrict__ gate_m,
                const float* __restrict__ gate_v, const float* __restrict__ gate_w2,
                const float* __restrict__ gate_b2,
                const float* __restrict__ attn_w1, const float* __restrict__ attn_g,
                const float* __restrict__ attn_b, const float* __restrict__ attn_m,
                const float* __restrict__ attn_v, const float* __restrict__ attn_w2,
                const float* __restrict__ attn_b2,
                float* __restrict__ out)
{
    __shared__ __align__(16) float W[WTOT];
    const int tid = threadIdx.x;

    // ---- stage transposed / BN-folded weights into LDS ----
    for (int i = tid; i < 64 * 64; i += 256) {
        int c = i & 63, j = i >> 6;
        W[W2T_O + i] = pos_w2[c * 64 + j];
    }
    for (int i = tid; i < 16 * 64; i += 256) {
        int c = i & 63, j = i >> 6;
        W[WA2T_O + i] = attn_w2[c * 16 + j];
    }
    if (tid < 64) {
        int c = tid;
        float st = trans_g[c] * rsqrtf(trans_v[c] + EPSV);
        #pragma unroll
        for (int i = 0; i < 6; ++i) W[WTT_O + i * 64 + c] = trans_w[c * 6 + i] * st;
        W[BT_O + c] = trans_b[c] - trans_m[c] * st;
        float sp = pos_g[c] * rsqrtf(pos_v[c] + EPSV);
        #pragma unroll
        for (int i = 0; i < 3; ++i) W[PP_O + c * 4 + i] = pos_w1[c * 3 + i] * sp;
        W[PP_O + c * 4 + 3] = pos_b[c] - pos_m[c] * sp;
        W[BP2_O + c] = pos_b2[c];
        W[AB2_O + c] = attn_b2[c];
    } else if (tid < 80) {
        int j = tid - 64;
        float sa = attn_g[j] * rsqrtf(attn_v[j] + EPSV);
        #pragma unroll
        for (int i = 0; i < 6; ++i) W[AP_O + j * 8 + i] = attn_w1[j * 6 + i] * sa;
        W[AP_O + j * 8 + 6] = attn_b[j] - attn_m[j] * sa;
        W[AP_O + j * 8 + 7] = 0.f;
    } else if (tid < 96) {
        int j = tid - 80;
        float sg = gate_g[j] * rsqrtf(gate_v[j] + EPSV);
        #pragma unroll
        for (int i = 0; i < 6; ++i) W[GP_O + j * 8 + i] = gate_w1[j * 6 + i] * sg;
        W[GP_O + j * 8 + 6] = gate_b[j] - gate_m[j] * sg;
        W[GP_O + j * 8 + 7] = gate_w2[j];
    } else if (tid == 96) {
        W[GB2_O] = gate_b2[0];
    }
    __syncthreads();

    const float4* PPv   = (const float4*)(W + PP_O);
    const float4* APv   = (const float4*)(W + AP_O);
    const float4* GPv   = (const float4*)(W + GP_O);
    const float4* W2Tv  = (const float4*)(W + W2T_O);
    const float4* WA2Tv = (const float4*)(W + WA2T_O);
    const float4* WTTv  = (const float4*)(W + WTT_O);
    const float4* BTv   = (const float4*)(W + BT_O);
    const float4* BP2v  = (const float4*)(W + BP2_O);
    const float4* AB2v  = (const float4*)(W + AB2_O);
    const float gb2 = W[GB2_O];

    // thread = (b,n) point x k-slice (4 slices of 5)
    const int g = blockIdx.x * 256 + tid;
    const int point = g >> 2;
    const int ks = g & 3;
    const int b = point >> 13;
    const int n = point & 8191;
    const float* xb = x + ((size_t)(b * 6) * 8192 + n) * 20 + ks * 5;

    #pragma unroll 1
    for (int cb = 0; cb < 4; ++cb) {          // 16 channels per pass
        const int q0 = cb * 4;                 // float4 column base
        float4 den[4], num[4], cmx[4];
        #pragma unroll
        for (int q = 0; q < 4; ++q) {
            den[q] = make_float4(0.f, 0.f, 0.f, 0.f);
            num[q] = make_float4(0.f, 0.f, 0.f, 0.f);
            cmx[q] = make_float4(-3.4e38f, -3.4e38f, -3.4e38f, -3.4e38f);
        }

        #pragma unroll 1
        for (int kk = 0; kk < 5; ++kk) {
            float xv[6];
            #pragma unroll
            for (int i = 0; i < 6; ++i) xv[i] = xb[(size_t)i * 163840 + kk];

            // 1) pos_enc: stream ph_j into 16-wide accumulator (only xv live)
            float4 pe[4];
            #pragma unroll
            for (int q = 0; q < 4; ++q) pe[q] = BP2v[q0 + q];
            #pragma unroll 4
            for (int j = 0; j < 64; ++j) {
                float4 pw = PPv[j];
                float phj = lrelu(pw.w + pw.x * xv[3] + pw.y * xv[4] + pw.z * xv[5]);
                #pragma unroll
                for (int q = 0; q < 4; ++q)
                    pe[q] = fma4(W2Tv[j * 16 + q0 + q], phj, pe[q]);
            }

            // 2) trans_feat
            float4 tf[4];
            #pragma unroll
            for (int q = 0; q < 4; ++q) tf[q] = BTv[q0 + q];
            #pragma unroll
            for (int i = 0; i < 6; ++i) {
                #pragma unroll
                for (int q = 0; q < 4; ++q)
                    tf[q] = fma4(WTTv[i * 16 + q0 + q], xv[i], tf[q]);
            }
            #pragma unroll
            for (int q = 0; q < 4; ++q) tf[q] = add4(lrelu4(tf[q]), pe[q]);

            // 3) logits: reuse pe regs; STREAM ah_j and gate (no ah[16] array)
            #pragma unroll
            for (int q = 0; q < 4; ++q) pe[q] = add4(AB2v[q0 + q], pe[q]);
            float ga = gb2;
            #pragma unroll 4
            for (int j = 0; j < 16; ++j) {
                float4 a0 = APv[j * 2], a1 = APv[j * 2 + 1];
                float ahj = lrelu(a0.x * xv[0] + a0.y * xv[1] + a0.z * xv[2] +
                                  a0.w * xv[3] + a1.x * xv[4] + a1.y * xv[5] + a1.z);
                #pragma unroll
                for (int q = 0; q < 4; ++q)
                    pe[q] = fma4(WA2Tv[j * 16 + q0 + q], ahj, pe[q]);
                float4 g0 = GPv[j * 2], g1 = GPv[j * 2 + 1];
                ga += g1.w * lrelu(g0.x * xv[0] + g0.y * xv[1] + g0.z * xv[2] +
                                   g0.w * xv[3] + g1.x * xv[4] + g1.y * xv[5] + g1.z);
            }
            const float gate = 1.f / (1.f + __expf(-ga));

            // 4) online accumulate
            #pragma unroll
            for (int q = 0; q < 4; ++q) {
                float4 e;
                e.x = __expf(pe[q].x); e.y = __expf(pe[q].y);
                e.z = __expf(pe[q].z); e.w = __expf(pe[q].w);
                den[q] = add4(den[q], e);
                num[q].x += tf[q].x * e.x; num[q].y += tf[q].y * e.y;
                num[q].z += tf[q].z * e.z; num[q].w += tf[q].w * e.w;
                cmx[q].x = fmaxf(cmx[q].x, tf[q].x * gate);
                cmx[q].y = fmaxf(cmx[q].y, tf[q].y * gate);
                cmx[q].z = fmaxf(cmx[q].z, tf[q].z * gate);
                cmx[q].w = fmaxf(cmx[q].w, tf[q].w * gate);
            }
        }

        // combine the 4 k-slices (lanes 4t..4t+3 share one (b,n))
        #pragma unroll
        for (int q = 0; q < 4; ++q) {
            float4 d = den[q], u = num[q], m = cmx[q];
            d.x += __shfl_xor(d.x, 1); d.x += __shfl_xor(d.x, 2);
            d.y += __shfl_xor(d.y, 1); d.y += __shfl_xor(d.y, 2);
            d.z += __shfl_xor(d.z, 1); d.z += __shfl_xor(d.z, 2);
            d.w += __shfl_xor(d.w, 1); d.w += __shfl_xor(d.w, 2);
            u.x += __shfl_xor(u.x, 1); u.x += __shfl_xor(u.x, 2);
            u.y += __shfl_xor(u.y, 1); u.y += __shfl_xor(u.y, 2);
            u.z += __shfl_xor(u.z, 1); u.z += __shfl_xor(u.z, 2);
            u.w += __shfl_xor(u.w, 1); u.w += __shfl_xor(u.w, 2);
            m.x = fmaxf(m.x, __shfl_xor(m.x, 1)); m.x = fmaxf(m.x, __shfl_xor(m.x, 2));
            m.y = fmaxf(m.y, __shfl_xor(m.y, 1)); m.y = fmaxf(m.y, __shfl_xor(m.y, 2));
            m.z = fmaxf(m.z, __shfl_xor(m.z, 1)); m.z = fmaxf(m.z, __shfl_xor(m.z, 2));
            m.w = fmaxf(m.w, __shfl_xor(m.w, 1)); m.w = fmaxf(m.w, __shfl_xor(m.w, 2));

            // channel c = cb*16 + q*4 + r; component r is written by lane with ks==r
            const size_t ob = ((size_t)(b * 64 + cb * 16 + q * 4)) * 8192 + n;
            if (ks == 0) out[ob]            = u.x / d.x + m.x;
            if (ks == 1) out[ob + 8192]     = u.y / d.y + m.y;
            if (ks == 2) out[ob + 16384]    = u.z / d.z + m.z;
            if (ks == 3) out[ob + 24576]    = u.w / d.w + m.w;
        }
    }
}

extern "C" void kernel_launch(void* const* d_in, const int* in_sizes, int n_in,
                              void* d_out, int out_size, void* d_ws, size_t ws_size,
                              hipStream_t stream) {
    const float* x       = (const float*)d_in[0];
    const float* trans_w = (const float*)d_in[1];
    const float* trans_g = (const float*)d_in[2];
    const float* trans_b = (const float*)d_in[3];
    const float* trans_m = (const float*)d_in[4];
    const float* trans_v = (const float*)d_in[5];
    const float* pos_w1  = (const float*)d_in[6];
    const float* pos_g   = (const float*)d_in[7];
    const float* pos_b   = (const float*)d_in[8];
    const float* pos_m   = (const float*)d_in[9];
    const float* pos_v   = (const float*)d_in[10];
    const float* pos_w2  = (const float*)d_in[11];
    const float* pos_b2  = (const float*)d_in[12];
    const float* gate_w1 = (const float*)d_in[13];
    const float* gate_g  = (const float*)d_in[14];
    const float* gate_b  = (const float*)d_in[15];
    const float* gate_m  = (const float*)d_in[16];
    const float* gate_v  = (const float*)d_in[17];
    const float* gate_w2 = (const float*)d_in[18];
    const float* gate_b2 = (const float*)d_in[19];
    const float* attn_w1 = (const float*)d_in[20];
    const float* attn_g  = (const float*)d_in[21];
    const float* attn_b  = (const float*)d_in[22];
    const float* attn_m  = (const float*)d_in[23];
    const float* attn_v  = (const float*)d_in[24];
    const float* attn_w2 = (const float*)d_in[25];
    const float* attn_b2 = (const float*)d_in[26];
    float* out = (float*)d_out;

    const int total_threads = 8 * 8192 * 4;   // 262144
    const int grid = total_threads / 256;     // 1024 blocks
    gsl_kernel<<<grid, 256, 0, stream>>>(
        x, trans_w, trans_g, trans_b, trans_m, trans_v,
        pos_w1, pos_g, pos_b, pos_m, pos_v, pos_w2, pos_b2,
        gate_w1, gate_g, gate_b, gate_m, gate_v, gate_w2, gate_b2,
        attn_w1, attn_g, attn_b, attn_m, attn_v, attn_w2, attn_b2,
        out);
}

// Round 6
// 209.884 us; speedup vs baseline: 68.1787x; 3.3756x over previous
//
#include <hip/hip_runtime.h>
#include <math.h>

#define NEG 0.2f
#define EPSV 1e-5f

typedef _Float16 v8h __attribute__((ext_vector_type(8)));
typedef _Float16 v4h __attribute__((ext_vector_type(4)));
typedef float    v4f __attribute__((ext_vector_type(4)));

__device__ __forceinline__ float lrelu(float v) { return fmaxf(v, NEG * v); }

#define MFMA(a, b, c) __builtin_amdgcn_mfma_f32_16x16x32_f16((a), (b), (c), 0, 0, 0)

// MFMA formulation: wave owns 16 consecutive n (point p = lane&15), loops k=0..19.
// All 1x1 convs are f16 MFMAs with M=channels, N=points, K=32:
//   A-frag: A[m=lane&15][k=quad*8+i] (weights, register-resident, loaded once)
//   B-frag: B[k=quad*8+i][n=lane&15] (activations)
//   C/D:    col(point)=lane&15, row(ch)=quad*4+reg (+16*mtile)
// One xv B-frag {xv0..5, 1.0, 0} feeds 10 input A-tiles (bias via k=6 column).
// ph/ah round-trip wave-private LDS (padded strides) into B-frags for pe/logits.
// Softmax-constant biases (ab2) dropped; pb2 rides pe's C-init (softmax-invariant).
__global__ __launch_bounds__(256, 1)
void gsl_mfma(const float* __restrict__ x,
              const float* __restrict__ trans_w, const float* __restrict__ trans_g,
              const float* __restrict__ trans_b, const float* __restrict__ trans_m,
              const float* __restrict__ trans_v,
              const float* __restrict__ pos_w1, const float* __restrict__ pos_g,
              const float* __restrict__ pos_b, const float* __restrict__ pos_m,
              const float* __restrict__ pos_v, const float* __restrict__ pos_w2,
              const float* __restrict__ pos_b2,
              const float* __restrict__ gate_w1, const float* __restrict__ gate_g,
              const float* __restrict__ gate_b, const float* __restrict__ gate_m,
              const float* __restrict__ gate_v, const float* __restrict__ gate_w2,
              const float* __restrict__ gate_b2,
              const float* __restrict__ attn_w1, const float* __restrict__ attn_g,
              const float* __restrict__ attn_b, const float* __restrict__ attn_m,
              const float* __restrict__ attn_v, const float* __restrict__ attn_w2,
              const float* __restrict__ attn_b2,
              float* __restrict__ out)
{
    __shared__ _Float16 PHB[4][1280];   // per-wave ph buffer: 16 pts x stride 80
    __shared__ _Float16 AHB[4][448];    // per-wave ah buffer: 16 pts x stride 24

    const int tid  = threadIdx.x;
    const int wv   = tid >> 6;
    const int lane = tid & 63;
    const int p    = lane & 15;   // point column / A-row index
    const int q    = lane >> 4;   // quad

    const int b = blockIdx.x >> 7;
    const int n = ((blockIdx.x & 127) << 6) | (wv << 4) | p;

    // ---- build register-resident A fragments (once) ----
    v8h W2f[4][2], WTf[4], WP1f[4], WA2f[4], WA1f, WG1f;
    v4f pb2v[4];
    #pragma unroll
    for (int mt = 0; mt < 4; ++mt) {
        const int ch = mt * 16 + p;
        #pragma unroll
        for (int h = 0; h < 2; ++h)
            #pragma unroll
            for (int i = 0; i < 8; ++i)
                W2f[mt][h][i] = (_Float16)pos_w2[ch * 64 + h * 32 + q * 8 + i];
        #pragma unroll
        for (int i = 0; i < 8; ++i) {
            int k = q * 8 + i;
            WA2f[mt][i] = (k < 16) ? (_Float16)attn_w2[ch * 16 + k] : (_Float16)0.f;
        }
        {
            float st = trans_g[ch] * rsqrtf(trans_v[ch] + EPSV);
            float bt = trans_b[ch] - trans_m[ch] * st;
            #pragma unroll
            for (int i = 0; i < 8; ++i) {
                int k = q * 8 + i;
                float v = (k < 6) ? trans_w[ch * 6 + k] * st : ((k == 6) ? bt : 0.f);
                WTf[mt][i] = (_Float16)v;
            }
        }
        {
            float sp = pos_g[ch] * rsqrtf(pos_v[ch] + EPSV);
            float bp = pos_b[ch] - pos_m[ch] * sp;
            #pragma unroll
            for (int i = 0; i < 8; ++i) {
                int k = q * 8 + i;
                float v = (k >= 3 && k < 6) ? pos_w1[ch * 3 + (k - 3)] * sp
                                            : ((k == 6) ? bp : 0.f);
                WP1f[mt][i] = (_Float16)v;
            }
        }
        #pragma unroll
        for (int r = 0; r < 4; ++r)
            pb2v[mt][r] = pos_b2[mt * 16 + 4 * q + r];
    }
    {
        float sa = attn_g[p] * rsqrtf(attn_v[p] + EPSV);
        float ba = attn_b[p] - attn_m[p] * sa;
        #pragma unroll
        for (int i = 0; i < 8; ++i) {
            int k = q * 8 + i;
            float v = (k < 6) ? attn_w1[p * 6 + k] * sa : ((k == 6) ? ba : 0.f);
            WA1f[i] = (_Float16)v;
        }
    }
    {
        float sg = gate_g[p] * rsqrtf(gate_v[p] + EPSV);
        float bg = gate_b[p] - gate_m[p] * sg;
        #pragma unroll
        for (int i = 0; i < 8; ++i) {
            int k = q * 8 + i;
            float v = (k < 6) ? gate_w1[p * 6 + k] * sg : ((k == 6) ? bg : 0.f);
            WG1f[i] = (_Float16)v;
        }
    }
    float g2w[4];
    #pragma unroll
    for (int r = 0; r < 4; ++r) g2w[r] = gate_w2[4 * q + r];
    const float gb2v = gate_b2[0];

    _Float16* PH = PHB[wv];
    _Float16* AH = AHB[wv];

    const v4f zero = {0.f, 0.f, 0.f, 0.f};
    v4f den[4], num[4], cmx[4];
    #pragma unroll
    for (int mt = 0; mt < 4; ++mt) {
        den[mt] = zero; num[mt] = zero;
        cmx[mt] = (v4f){-3.4e38f, -3.4e38f, -3.4e38f, -3.4e38f};
    }

    const float* xb = x + ((size_t)(b * 6) * 8192 + n) * 20;
    float nx[6];
    #pragma unroll
    for (int c = 0; c < 6; ++c) nx[c] = xb[(size_t)c * 163840];

    #pragma unroll 1
    for (int k = 0; k < 20; ++k) {
        // build xv B-frag; prefetch next k
        v8h xvf;
        #pragma unroll
        for (int c = 0; c < 6; ++c) xvf[c] = (_Float16)nx[c];
        xvf[6] = (_Float16)1.f;
        xvf[7] = (_Float16)0.f;
        const int kn = (k < 19) ? k + 1 : 19;
        #pragma unroll
        for (int c = 0; c < 6; ++c) nx[c] = xb[(size_t)c * 163840 + kn];

        // input GEMMs (shared B-frag)
        v4f tfa[4], php[4];
        #pragma unroll
        for (int mt = 0; mt < 4; ++mt) tfa[mt] = MFMA(WTf[mt], xvf, zero);
        #pragma unroll
        for (int mt = 0; mt < 4; ++mt) php[mt] = MFMA(WP1f[mt], xvf, zero);
        v4f ahp = MFMA(WA1f, xvf, zero);
        v4f ghp = MFMA(WG1f, xvf, zero);

        // ph, ah -> lrelu -> wave-private LDS (B-frag layout)
        #pragma unroll
        for (int mt = 0; mt < 4; ++mt) {
            v4h v;
            #pragma unroll
            for (int r = 0; r < 4; ++r) v[r] = (_Float16)lrelu(php[mt][r]);
            *(v4h*)(PH + p * 80 + mt * 16 + 4 * q) = v;
        }
        {
            v4h v;
            #pragma unroll
            for (int r = 0; r < 4; ++r) v[r] = (_Float16)lrelu(ahp[r]);
            *(v4h*)(AH + p * 24 + 4 * q) = v;
        }

        // gate scalar: partial dot + cross-quad reduce
        float ga = 0.f;
        #pragma unroll
        for (int r = 0; r < 4; ++r) ga += g2w[r] * lrelu(ghp[r]);
        ga += __shfl_xor(ga, 16);
        ga += __shfl_xor(ga, 32);
        const float gate = 1.f / (1.f + __expf(-(ga + gb2v)));

        // re-read as B-frags (same-wave producer; compiler inserts lgkmcnt)
        v8h phf0 = *(const v8h*)(PH + p * 80 + 8 * q);
        v8h phf1 = *(const v8h*)(PH + p * 80 + 32 + 8 * q);
        v8h ahf  = *(const v8h*)(AH + p * 24 + 8 * q);  // q>=2 garbage, A=0 there

        // pe GEMM (C-init = pb2; constant shift is softmax-invariant in logits)
        v4f pe[4];
        #pragma unroll
        for (int mt = 0; mt < 4; ++mt) {
            pe[mt] = MFMA(W2f[mt][0], phf0, pb2v[mt]);
            pe[mt] = MFMA(W2f[mt][1], phf1, pe[mt]);
        }

        // epilogue per mtile: tf, then logits in-place, then online softmax/max
        #pragma unroll
        for (int mt = 0; mt < 4; ++mt) {
            v4f tfv;
            #pragma unroll
            for (int r = 0; r < 4; ++r) tfv[r] = lrelu(tfa[mt][r]) + pe[mt][r];
            pe[mt] = MFMA(WA2f[mt], ahf, pe[mt]);   // logits (+const, invariant)
            #pragma unroll
            for (int r = 0; r < 4; ++r) {
                float e = __expf(pe[mt][r]);
                den[mt][r] += e;
                num[mt][r] += tfv[r] * e;
                cmx[mt][r] = fmaxf(cmx[mt][r], tfv[r] * gate);
            }
        }
    }

    // write out: lane owns channels mt*16 + 4q + r for its point n
    #pragma unroll
    for (int mt = 0; mt < 4; ++mt) {
        #pragma unroll
        for (int r = 0; r < 4; ++r) {
            const int ch = mt * 16 + 4 * q + r;
            out[((size_t)(b * 64 + ch)) * 8192 + n] =
                num[mt][r] / den[mt][r] + cmx[mt][r];
        }
    }
}

extern "C" void kernel_launch(void* const* d_in, const int* in_sizes, int n_in,
                              void* d_out, int out_size, void* d_ws, size_t ws_size,
                              hipStream_t stream) {
    const float* x       = (const float*)d_in[0];
    const float* trans_w = (const float*)d_in[1];
    const float* trans_g = (const float*)d_in[2];
    const float* trans_b = (const float*)d_in[3];
    const float* trans_m = (const float*)d_in[4];
    const float* trans_v = (const float*)d_in[5];
    const float* pos_w1  = (const float*)d_in[6];
    const float* pos_g   = (const float*)d_in[7];
    const float* pos_b   = (const float*)d_in[8];
    const float* pos_m   = (const float*)d_in[9];
    const float* pos_v   = (const float*)d_in[10];
    const float* pos_w2  = (const float*)d_in[11];
    const float* pos_b2  = (const float*)d_in[12];
    const float* gate_w1 = (const float*)d_in[13];
    const float* gate_g  = (const float*)d_in[14];
    const float* gate_b  = (const float*)d_in[15];
    const float* gate_m  = (const float*)d_in[16];
    const float* gate_v  = (const float*)d_in[17];
    const float* gate_w2 = (const float*)d_in[18];
    const float* gate_b2 = (const float*)d_in[19];
    const float* attn_w1 = (const float*)d_in[20];
    const float* attn_g  = (const float*)d_in[21];
    const float* attn_b  = (const float*)d_in[22];
    const float* attn_m  = (const float*)d_in[23];
    const float* attn_v  = (const float*)d_in[24];
    const float* attn_w2 = (const float*)d_in[25];
    const float* attn_b2 = (const float*)d_in[26];
    float* out = (float*)d_out;

    // 8 b * 128 blocks/b; block = 4 waves * 16 points
    gsl_mfma<<<1024, 256, 0, stream>>>(
        x, trans_w, trans_g, trans_b, trans_m, trans_v,
        pos_w1, pos_g, pos_b, pos_m, pos_v, pos_w2, pos_b2,
        gate_w1, gate_g, gate_b, gate_m, gate_v, gate_w2, gate_b2,
        attn_w1, attn_g, attn_b, attn_m, attn_v, attn_w2, attn_b2,
        out);
}

// Round 8
// 206.591 us; speedup vs baseline: 69.2657x; 1.0159x over previous
//
#include <hip/hip_runtime.h>
#include <math.h>

#define NEG 0.2f
#define EPSV 1e-5f

typedef _Float16 v8h __attribute__((ext_vector_type(8)));
typedef _Float16 v4h __attribute__((ext_vector_type(4)));
typedef _Float16 v2h __attribute__((ext_vector_type(2)));
typedef __fp16   f16x2 __attribute__((ext_vector_type(2)));
typedef float    v4f __attribute__((ext_vector_type(4)));

__device__ __forceinline__ float lrelu(float v) { return fmaxf(v, NEG * v); }

// cvt_pkrtz returns __fp16x2; bit-cast to _Float16x2 (same layout)
__device__ __forceinline__ v2h pk(float a, float b) {
    union { f16x2 i; v2h o; } u;
    u.i = __builtin_amdgcn_cvt_pkrtz(a, b);
    return u.o;
}

#define MFMA(a, b, c) __builtin_amdgcn_mfma_f32_16x16x32_f16((a), (b), (c), 0, 0, 0)

// MFMA mapping (verified round 6): wave owns 16 n (p = lane&15), loops k=0..19.
//   A-frag: A[m=lane&15][k=quad*8+i] (weights, register/AGPR-resident)
//   B-frag: B[k=quad*8+i][n=lane&15] (activations)
//   C/D:    col(point)=lane&15, row(ch)=quad*4+reg (+16*mtile)
// Round 8 (= round 7 with compile fix): software-pipelined k-loop with
// double-buffered PH/AH (reads for k issued before produce(k+1) writes ->
// LDS round-trip latency hidden), PH stride 80->72 halves (36 words: only
// p/p+8 alias = 2-way = free; 80h was 4-way), cvt_pkrtz packing.
__global__ __launch_bounds__(256, 1)
void gsl_mfma(const float* __restrict__ x,
              const float* __restrict__ trans_w, const float* __restrict__ trans_g,
              const float* __restrict__ trans_b, const float* __restrict__ trans_m,
              const float* __restrict__ trans_v,
              const float* __restrict__ pos_w1, const float* __restrict__ pos_g,
              const float* __restrict__ pos_b, const float* __restrict__ pos_m,
              const float* __restrict__ pos_v, const float* __restrict__ pos_w2,
              const float* __restrict__ pos_b2,
              const float* __restrict__ gate_w1, const float* __restrict__ gate_g,
              const float* __restrict__ gate_b, const float* __restrict__ gate_m,
              const float* __restrict__ gate_v, const float* __restrict__ gate_w2,
              const float* __restrict__ gate_b2,
              const float* __restrict__ attn_w1, const float* __restrict__ attn_g,
              const float* __restrict__ attn_b, const float* __restrict__ attn_m,
              const float* __restrict__ attn_v, const float* __restrict__ attn_w2,
              const float* __restrict__ attn_b2,
              float* __restrict__ out)
{
    __shared__ _Float16 PHB[4][2][1152];  // per-wave, dbuf: 16 pts x stride 72
    __shared__ _Float16 AHB[4][2][448];   // per-wave, dbuf: 16 pts x stride 24 (+pad)

    const int tid  = threadIdx.x;
    const int wv   = tid >> 6;
    const int lane = tid & 63;
    const int p    = lane & 15;
    const int q    = lane >> 4;

    const int b = blockIdx.x >> 7;
    const int n = ((blockIdx.x & 127) << 6) | (wv << 4) | p;

    // zero AH pad zones (q>=2 frag reads hit them; 0 * garbage-NaN would poison)
    {
        _Float16* AH0 = &AHB[wv][0][0];
        const v4h zh = {(_Float16)0.f, (_Float16)0.f, (_Float16)0.f, (_Float16)0.f};
        for (int i = lane; i < 224; i += 64) *(v4h*)(AH0 + 4 * i) = zh;
    }

    // ---- register-resident A fragments (built once) ----
    v8h W2f[4][2], WTf[4], WP1f[4], WA2f[4], WA1f, WG1f;
    v4f pb2v[4];
    #pragma unroll
    for (int mt = 0; mt < 4; ++mt) {
        const int ch = mt * 16 + p;
        #pragma unroll
        for (int h = 0; h < 2; ++h)
            #pragma unroll
            for (int i = 0; i < 8; ++i)
                W2f[mt][h][i] = (_Float16)pos_w2[ch * 64 + h * 32 + q * 8 + i];
        #pragma unroll
        for (int i = 0; i < 8; ++i) {
            int k = q * 8 + i;
            WA2f[mt][i] = (k < 16) ? (_Float16)attn_w2[ch * 16 + k] : (_Float16)0.f;
        }
        {
            float st = trans_g[ch] * rsqrtf(trans_v[ch] + EPSV);
            float bt = trans_b[ch] - trans_m[ch] * st;
            #pragma unroll
            for (int i = 0; i < 8; ++i) {
                int k = q * 8 + i;
                float v = (k < 6) ? trans_w[ch * 6 + k] * st : ((k == 6) ? bt : 0.f);
                WTf[mt][i] = (_Float16)v;
            }
        }
        {
            float sp = pos_g[ch] * rsqrtf(pos_v[ch] + EPSV);
            float bp = pos_b[ch] - pos_m[ch] * sp;
            #pragma unroll
            for (int i = 0; i < 8; ++i) {
                int k = q * 8 + i;
                float v = (k >= 3 && k < 6) ? pos_w1[ch * 3 + (k - 3)] * sp
                                            : ((k == 6) ? bp : 0.f);
                WP1f[mt][i] = (_Float16)v;
            }
        }
        #pragma unroll
        for (int r = 0; r < 4; ++r)
            pb2v[mt][r] = pos_b2[mt * 16 + 4 * q + r];
    }
    {
        float sa = attn_g[p] * rsqrtf(attn_v[p] + EPSV);
        float ba = attn_b[p] - attn_m[p] * sa;
        #pragma unroll
        for (int i = 0; i < 8; ++i) {
            int k = q * 8 + i;
            float v = (k < 6) ? attn_w1[p * 6 + k] * sa : ((k == 6) ? ba : 0.f);
            WA1f[i] = (_Float16)v;
        }
    }
    {
        float sg = gate_g[p] * rsqrtf(gate_v[p] + EPSV);
        float bg = gate_b[p] - gate_m[p] * sg;
        #pragma unroll
        for (int i = 0; i < 8; ++i) {
            int k = q * 8 + i;
            float v = (k < 6) ? gate_w1[p * 6 + k] * sg : ((k == 6) ? bg : 0.f);
            WG1f[i] = (_Float16)v;
        }
    }
    float g2w[4];
    #pragma unroll
    for (int r = 0; r < 4; ++r) g2w[r] = gate_w2[4 * q + r];
    const float gb2v = gate_b2[0];

    _Float16* const PHbase = &PHB[wv][0][0];
    _Float16* const AHbase = &AHB[wv][0][0];

    const v4f zero = {0.f, 0.f, 0.f, 0.f};
    v4f den[4], num[4], cmx[4];
    #pragma unroll
    for (int mt = 0; mt < 4; ++mt) {
        den[mt] = zero; num[mt] = zero;
        cmx[mt] = (v4f){-3.4e38f, -3.4e38f, -3.4e38f, -3.4e38f};
    }

    const float* xb = x + ((size_t)(b * 6) * 8192 + n) * 20;

    // ---- pipeline prologue: k=0 produce ----
    float nx[6];
    #pragma unroll
    for (int c = 0; c < 6; ++c) nx[c] = xb[(size_t)c * 163840];

    v8h xv_cur;
    {
        union { v8h v; v2h h[4]; } u;
        u.h[0] = pk(nx[0], nx[1]);
        u.h[1] = pk(nx[2], nx[3]);
        u.h[2] = pk(nx[4], nx[5]);
        u.h[3] = (v2h){(_Float16)1.f, (_Float16)0.f};
        xv_cur = u.v;
    }
    #pragma unroll
    for (int c = 0; c < 6; ++c) nx[c] = xb[(size_t)c * 163840 + 1];

    {   // produce(0) into buffer 0
        v4f php[4];
        #pragma unroll
        for (int mt = 0; mt < 4; ++mt) php[mt] = MFMA(WP1f[mt], xv_cur, zero);
        v4f ahp = MFMA(WA1f, xv_cur, zero);
        _Float16* PHW = PHbase + p * 72 + 4 * q;
        #pragma unroll
        for (int mt = 0; mt < 4; ++mt) {
            union { v4h v; v2h h[2]; } u;
            u.h[0] = pk(lrelu(php[mt][0]), lrelu(php[mt][1]));
            u.h[1] = pk(lrelu(php[mt][2]), lrelu(php[mt][3]));
            *(v4h*)(PHW + mt * 16) = u.v;
        }
        union { v4h v; v2h h[2]; } ua;
        ua.h[0] = pk(lrelu(ahp[0]), lrelu(ahp[1]));
        ua.h[1] = pk(lrelu(ahp[2]), lrelu(ahp[3]));
        *(v4h*)(AHbase + p * 24 + 4 * q) = ua.v;
    }

    #pragma unroll 1
    for (int k = 0; k < 20; ++k) {
        const int sel = k & 1;
        // 1) issue reads for k (writes landed last iteration)
        _Float16* PH = PHbase + sel * 1152;
        _Float16* AH = AHbase + sel * 448;
        v8h phf0 = *(const v8h*)(PH + p * 72 + 8 * q);
        v8h phf1 = *(const v8h*)(PH + p * 72 + 32 + 8 * q);
        v8h ahf  = *(const v8h*)(AH + p * 24 + 8 * q);

        // 2) produce(k+1) into the other buffer
        v8h xv_nxt = xv_cur;
        if (k < 19) {
            union { v8h v; v2h h[4]; } u;
            u.h[0] = pk(nx[0], nx[1]);
            u.h[1] = pk(nx[2], nx[3]);
            u.h[2] = pk(nx[4], nx[5]);
            u.h[3] = (v2h){(_Float16)1.f, (_Float16)0.f};
            xv_nxt = u.v;
            const int kn = (k < 18) ? k + 2 : 19;
            #pragma unroll
            for (int c = 0; c < 6; ++c) nx[c] = xb[(size_t)c * 163840 + kn];

            v4f php[4];
            #pragma unroll
            for (int mt = 0; mt < 4; ++mt) php[mt] = MFMA(WP1f[mt], xv_nxt, zero);
            v4f ahp = MFMA(WA1f, xv_nxt, zero);
            _Float16* PHW = PHbase + (sel ^ 1) * 1152 + p * 72 + 4 * q;
            #pragma unroll
            for (int mt = 0; mt < 4; ++mt) {
                union { v4h v; v2h h[2]; } uu;
                uu.h[0] = pk(lrelu(php[mt][0]), lrelu(php[mt][1]));
                uu.h[1] = pk(lrelu(php[mt][2]), lrelu(php[mt][3]));
                *(v4h*)(PHW + mt * 16) = uu.v;
            }
            union { v4h v; v2h h[2]; } ua;
            ua.h[0] = pk(lrelu(ahp[0]), lrelu(ahp[1]));
            ua.h[1] = pk(lrelu(ahp[2]), lrelu(ahp[3]));
            *(v4h*)(AHbase + (sel ^ 1) * 448 + p * 24 + 4 * q) = ua.v;
        }

        // 3) consume(k): trans + gate from xv_cur
        v4f tfa[4];
        #pragma unroll
        for (int mt = 0; mt < 4; ++mt) tfa[mt] = MFMA(WTf[mt], xv_cur, zero);
        v4f ghp = MFMA(WG1f, xv_cur, zero);
        float ga = 0.f;
        #pragma unroll
        for (int r = 0; r < 4; ++r) ga += g2w[r] * lrelu(ghp[r]);
        ga += __shfl_xor(ga, 16);
        ga += __shfl_xor(ga, 32);
        const float gate = 1.f / (1.f + __expf(-(ga + gb2v)));

        // pe GEMM (C-init = pb2; constant shift is softmax-invariant in logits)
        v4f pe[4];
        #pragma unroll
        for (int mt = 0; mt < 4; ++mt) {
            pe[mt] = MFMA(W2f[mt][0], phf0, pb2v[mt]);
            pe[mt] = MFMA(W2f[mt][1], phf1, pe[mt]);
        }

        #pragma unroll
        for (int mt = 0; mt < 4; ++mt) {
            v4f tfv;
            #pragma unroll
            for (int r = 0; r < 4; ++r) tfv[r] = lrelu(tfa[mt][r]) + pe[mt][r];
            pe[mt] = MFMA(WA2f[mt], ahf, pe[mt]);   // logits (+const, invariant)
            #pragma unroll
            for (int r = 0; r < 4; ++r) {
                float e = __expf(pe[mt][r]);
                den[mt][r] += e;
                num[mt][r] += tfv[r] * e;
                cmx[mt][r] = fmaxf(cmx[mt][r], tfv[r] * gate);
            }
        }
        xv_cur = xv_nxt;
    }

    // write out: lane owns channels mt*16 + 4q + r for its point n
    #pragma unroll
    for (int mt = 0; mt < 4; ++mt) {
        #pragma unroll
        for (int r = 0; r < 4; ++r) {
            const int ch = mt * 16 + 4 * q + r;
            out[((size_t)(b * 64 + ch)) * 8192 + n] =
                num[mt][r] / den[mt][r] + cmx[mt][r];
        }
    }
}

extern "C" void kernel_launch(void* const* d_in, const int* in_sizes, int n_in,
                              void* d_out, int out_size, void* d_ws, size_t ws_size,
                              hipStream_t stream) {
    const float* x       = (const float*)d_in[0];
    const float* trans_w = (const float*)d_in[1];
    const float* trans_g = (const float*)d_in[2];
    const float* trans_b = (const float*)d_in[3];
    const float* trans_m = (const float*)d_in[4];
    const float* trans_v = (const float*)d_in[5];
    const float* pos_w1  = (const float*)d_in[6];
    const float* pos_g   = (const float*)d_in[7];
    const float* pos_b   = (const float*)d_in[8];
    const float* pos_m   = (const float*)d_in[9];
    const float* pos_v   = (const float*)d_in[10];
    const float* pos_w2  = (const float*)d_in[11];
    const float* pos_b2  = (const float*)d_in[12];
    const float* gate_w1 = (const float*)d_in[13];
    const float* gate_g  = (const float*)d_in[14];
    const float* gate_b  = (const float*)d_in[15];
    const float* gate_m  = (const float*)d_in[16];
    const float* gate_v  = (const float*)d_in[17];
    const float* gate_w2 = (const float*)d_in[18];
    const float* gate_b2 = (const float*)d_in[19];
    const float* attn_w1 = (const float*)d_in[20];
    const float* attn_g  = (const float*)d_in[21];
    const float* attn_b  = (const float*)d_in[22];
    const float* attn_m  = (const float*)d_in[23];
    const float* attn_v  = (const float*)d_in[24];
    const float* attn_w2 = (const float*)d_in[25];
    const float* attn_b2 = (const float*)d_in[26];
    float* out = (float*)d_out;

    // 8 b * 128 blocks/b; block = 4 waves * 16 points
    gsl_mfma<<<1024, 256, 0, stream>>>(
        x, trans_w, trans_g, trans_b, trans_m, trans_v,
        pos_w1, pos_g, pos_b, pos_m, pos_v, pos_w2, pos_b2,
        gate_w1, gate_g, gate_b, gate_m, gate_v, gate_w2, gate_b2,
        attn_w1, attn_g, attn_b, attn_m, attn_v, attn_w2, attn_b2,
        out);
}

// Round 9
// 197.884 us; speedup vs baseline: 72.3135x; 1.0440x over previous
//
#include <hip/hip_runtime.h>
#include <math.h>

#define NEG 0.2f
#define EPSV 1e-5f

typedef _Float16 v8h __attribute__((ext_vector_type(8)));
typedef _Float16 v4h __attribute__((ext_vector_type(4)));
typedef _Float16 v2h __attribute__((ext_vector_type(2)));
typedef __fp16   f16x2 __attribute__((ext_vector_type(2)));
typedef float    v4f __attribute__((ext_vector_type(4)));

__device__ __forceinline__ float lrelu(float v) { return fmaxf(v, NEG * v); }
__device__ __forceinline__ v4f lrelu4(v4f v) {
    return __builtin_elementwise_max(v, v * NEG);
}
__device__ __forceinline__ v2h lreluh2(v2h v) {
    return __builtin_elementwise_max(v, v * (_Float16)NEG);
}

// cvt_pkrtz returns __fp16x2; bit-cast to _Float16x2 (same layout)
__device__ __forceinline__ v2h pk(float a, float b) {
    union { f16x2 i; v2h o; } u;
    u.i = __builtin_amdgcn_cvt_pkrtz(a, b);
    return u.o;
}

#define MFMA(a, b, c) __builtin_amdgcn_mfma_f32_16x16x32_f16((a), (b), (c), 0, 0, 0)

// MFMA mapping (verified round 6): wave owns 16 n (p = lane&15), loops k=0..19.
//   A-frag: A[m=lane&15][k=quad*8+i], B-frag: B[k=quad*8+i][n=lane&15]
//   C/D: col(point)=lane&15, row(ch)=quad*4+reg (+16*mtile)
// Round 9: rounds 6/8 both landed 103us at ~2 waves/SIMD (reg-limited:
// 120 VGPR + ~56 AGPR). Loop-invariant produce-side weights (WP1/WA1/WG1/pb2,
// ~56 regs) move to block-shared LDS, re-read per iter (~10 ds_read_b128,
// cheap) -> total regs ~150 -> 3 waves/SIMD for +50% latency hiding.
// Rows padded to 40h (20 words: only p/p+8 bank-alias = free 2-way).
__global__ __launch_bounds__(256, 1)
void gsl_mfma(const float* __restrict__ x,
              const float* __restrict__ trans_w, const float* __restrict__ trans_g,
              const float* __restrict__ trans_b, const float* __restrict__ trans_m,
              const float* __restrict__ trans_v,
              const float* __restrict__ pos_w1, const float* __restrict__ pos_g,
              const float* __restrict__ pos_b, const float* __restrict__ pos_m,
              const float* __restrict__ pos_v, const float* __restrict__ pos_w2,
              const float* __restrict__ pos_b2,
              const float* __restrict__ gate_w1, const float* __restrict__ gate_g,
              const float* __restrict__ gate_b, const float* __restrict__ gate_m,
              const float* __restrict__ gate_v, const float* __restrict__ gate_w2,
              const float* __restrict__ gate_b2,
              const float* __restrict__ attn_w1, const float* __restrict__ attn_g,
              const float* __restrict__ attn_b, const float* __restrict__ attn_m,
              const float* __restrict__ attn_v, const float* __restrict__ attn_w2,
              const float* __restrict__ attn_b2,
              float* __restrict__ out)
{
    __shared__ _Float16 WH[3840];        // WP1 tiles(4*640) | WA1(640) | WG1(640)
    __shared__ float    PB2[64];
    __shared__ _Float16 PHB[4][2][1152]; // per-wave dbuf: 16 pts x stride 72
    __shared__ _Float16 AHB[4][2][448];  // per-wave dbuf: 16 pts x stride 24

    const int tid  = threadIdx.x;
    const int wv   = tid >> 6;
    const int lane = tid & 63;
    const int p    = lane & 15;
    const int q    = lane >> 4;

    const int b = blockIdx.x >> 7;
    const int n = ((blockIdx.x & 127) << 6) | (wv << 4) | p;

    // zero AH pad zones (q>=2 frag reads hit them; 0 * garbage-NaN would poison)
    {
        _Float16* AH0 = &AHB[wv][0][0];
        const v4h zh = {(_Float16)0.f, (_Float16)0.f, (_Float16)0.f, (_Float16)0.f};
        for (int i = lane; i < 224; i += 64) *(v4h*)(AH0 + 4 * i) = zh;
    }

    // ---- stage produce-side weights in block-shared LDS (frees ~56 VGPRs) ----
    if (tid < 64) {
        const int c = tid;
        float sp = pos_g[c] * rsqrtf(pos_v[c] + EPSV);
        float bp = pos_b[c] - pos_m[c] * sp;
        _Float16* row = WH + (c >> 4) * 640 + (c & 15) * 40;
        for (int k = 0; k < 40; ++k) {
            float v = (k >= 3 && k < 6) ? pos_w1[c * 3 + (k - 3)] * sp
                                        : ((k == 6) ? bp : 0.f);
            row[k] = (_Float16)v;
        }
        PB2[c] = pos_b2[c];
    } else if (tid < 80) {
        const int j = tid - 64;
        float sa = attn_g[j] * rsqrtf(attn_v[j] + EPSV);
        float ba = attn_b[j] - attn_m[j] * sa;
        _Float16* row = WH + 2560 + j * 40;
        for (int k = 0; k < 40; ++k)
            row[k] = (_Float16)((k < 6) ? attn_w1[j * 6 + k] * sa
                                        : ((k == 6) ? ba : 0.f));
    } else if (tid < 96) {
        const int j = tid - 80;
        float sg = gate_g[j] * rsqrtf(gate_v[j] + EPSV);
        float bg = gate_b[j] - gate_m[j] * sg;
        _Float16* row = WH + 3200 + j * 40;
        for (int k = 0; k < 40; ++k)
            row[k] = (_Float16)((k < 6) ? gate_w1[j * 6 + k] * sg
                                        : ((k == 6) ? bg : 0.f));
    }

    // ---- persistent A-frags: only W2f/WTf/WA2f stay in registers (64 VGPRs) ----
    v8h W2f[4][2], WTf[4], WA2f[4];
    #pragma unroll
    for (int mt = 0; mt < 4; ++mt) {
        const int ch = mt * 16 + p;
        #pragma unroll
        for (int h = 0; h < 2; ++h)
            #pragma unroll
            for (int i = 0; i < 8; ++i)
                W2f[mt][h][i] = (_Float16)pos_w2[ch * 64 + h * 32 + q * 8 + i];
        #pragma unroll
        for (int i = 0; i < 8; ++i) {
            int k = q * 8 + i;
            WA2f[mt][i] = (k < 16) ? (_Float16)attn_w2[ch * 16 + k] : (_Float16)0.f;
        }
        float st = trans_g[ch] * rsqrtf(trans_v[ch] + EPSV);
        float bt = trans_b[ch] - trans_m[ch] * st;
        #pragma unroll
        for (int i = 0; i < 8; ++i) {
            int k = q * 8 + i;
            float v = (k < 6) ? trans_w[ch * 6 + k] * st : ((k == 6) ? bt : 0.f);
            WTf[mt][i] = (_Float16)v;
        }
    }
    float g2w[4];
    #pragma unroll
    for (int r = 0; r < 4; ++r) g2w[r] = gate_w2[4 * q + r];
    const float gb2v = gate_b2[0];

    __syncthreads();   // WH/PB2 visible to all waves

    const _Float16* const WP1p = WH + p * 40 + q * 8;          // + mt*640
    const _Float16* const WA1p = WH + 2560 + p * 40 + q * 8;
    const _Float16* const WG1p = WH + 3200 + p * 40 + q * 8;
    const float* const    PB2p = PB2 + 4 * q;                  // + mt*16

    _Float16* const PHbase = &PHB[wv][0][0];
    _Float16* const AHbase = &AHB[wv][0][0];

    const v4f zero = {0.f, 0.f, 0.f, 0.f};
    v4f den[4], num[4], cmx[4];
    #pragma unroll
    for (int mt = 0; mt < 4; ++mt) {
        den[mt] = zero; num[mt] = zero;
        cmx[mt] = (v4f){-3.4e38f, -3.4e38f, -3.4e38f, -3.4e38f};
    }

    const float* xb = x + ((size_t)(b * 6) * 8192 + n) * 20;

    // ---- pipeline prologue: k=0 produce ----
    float nx[6];
    #pragma unroll
    for (int c = 0; c < 6; ++c) nx[c] = xb[(size_t)c * 163840];

    v8h xv_cur;
    {
        union { v8h v; v2h h[4]; } u;
        u.h[0] = pk(nx[0], nx[1]);
        u.h[1] = pk(nx[2], nx[3]);
        u.h[2] = pk(nx[4], nx[5]);
        u.h[3] = (v2h){(_Float16)1.f, (_Float16)0.f};
        xv_cur = u.v;
    }
    #pragma unroll
    for (int c = 0; c < 6; ++c) nx[c] = xb[(size_t)c * 163840 + 1];

    {   // produce(0) into buffer 0
        v4f php[4];
        #pragma unroll
        for (int mt = 0; mt < 4; ++mt)
            php[mt] = MFMA(*(const v8h*)(WP1p + mt * 640), xv_cur, zero);
        v4f ahp = MFMA(*(const v8h*)WA1p, xv_cur, zero);
        _Float16* PHW = PHbase + p * 72 + 4 * q;
        #pragma unroll
        for (int mt = 0; mt < 4; ++mt) {
            union { v4h v; v2h h[2]; } u;
            u.h[0] = lreluh2(pk(php[mt][0], php[mt][1]));
            u.h[1] = lreluh2(pk(php[mt][2], php[mt][3]));
            *(v4h*)(PHW + mt * 16) = u.v;
        }
        union { v4h v; v2h h[2]; } ua;
        ua.h[0] = lreluh2(pk(ahp[0], ahp[1]));
        ua.h[1] = lreluh2(pk(ahp[2], ahp[3]));
        *(v4h*)(AHbase + p * 24 + 4 * q) = ua.v;
    }

    #pragma unroll 1
    for (int k = 0; k < 20; ++k) {
        const int sel = k & 1;
        // 1) issue reads for k (writes landed last iteration)
        _Float16* PH = PHbase + sel * 1152;
        _Float16* AH = AHbase + sel * 448;
        v8h phf0 = *(const v8h*)(PH + p * 72 + 8 * q);
        v8h phf1 = *(const v8h*)(PH + p * 72 + 32 + 8 * q);
        v8h ahf  = *(const v8h*)(AH + p * 24 + 8 * q);

        // 2) produce(k+1) into the other buffer
        v8h xv_nxt = xv_cur;
        if (k < 19) {
            union { v8h v; v2h h[4]; } u;
            u.h[0] = pk(nx[0], nx[1]);
            u.h[1] = pk(nx[2], nx[3]);
            u.h[2] = pk(nx[4], nx[5]);
            u.h[3] = (v2h){(_Float16)1.f, (_Float16)0.f};
            xv_nxt = u.v;
            const int kn = (k < 18) ? k + 2 : 19;
            #pragma unroll
            for (int c = 0; c < 6; ++c) nx[c] = xb[(size_t)c * 163840 + kn];

            v4f php[4];
            #pragma unroll
            for (int mt = 0; mt < 4; ++mt)
                php[mt] = MFMA(*(const v8h*)(WP1p + mt * 640), xv_nxt, zero);
            v4f ahp = MFMA(*(const v8h*)WA1p, xv_nxt, zero);
            _Float16* PHW = PHbase + (sel ^ 1) * 1152 + p * 72 + 4 * q;
            #pragma unroll
            for (int mt = 0; mt < 4; ++mt) {
                union { v4h v; v2h h[2]; } uu;
                uu.h[0] = lreluh2(pk(php[mt][0], php[mt][1]));
                uu.h[1] = lreluh2(pk(php[mt][2], php[mt][3]));
                *(v4h*)(PHW + mt * 16) = uu.v;
            }
            union { v4h v; v2h h[2]; } ua;
            ua.h[0] = lreluh2(pk(ahp[0], ahp[1]));
            ua.h[1] = lreluh2(pk(ahp[2], ahp[3]));
            *(v4h*)(AHbase + (sel ^ 1) * 448 + p * 24 + 4 * q) = ua.v;
        }

        // 3) consume(k): trans + gate from xv_cur
        v4f tfa[4];
        #pragma unroll
        for (int mt = 0; mt < 4; ++mt) tfa[mt] = MFMA(WTf[mt], xv_cur, zero);
        v4f ghp = MFMA(*(const v8h*)WG1p, xv_cur, zero);
        float ga = 0.f;
        #pragma unroll
        for (int r = 0; r < 4; ++r) ga += g2w[r] * lrelu(ghp[r]);
        ga += __shfl_xor(ga, 16);
        ga += __shfl_xor(ga, 32);
        const float gate = 1.f / (1.f + __expf(-(ga + gb2v)));

        // pe GEMM (C-init = pb2 from LDS; constant shift softmax-invariant)
        v4f pe[4];
        #pragma unroll
        for (int mt = 0; mt < 4; ++mt) {
            pe[mt] = MFMA(W2f[mt][0], phf0, *(const v4f*)(PB2p + mt * 16));
            pe[mt] = MFMA(W2f[mt][1], phf1, pe[mt]);
        }

        #pragma unroll
        for (int mt = 0; mt < 4; ++mt) {
            v4f tfv = lrelu4(tfa[mt]) + pe[mt];
            pe[mt] = MFMA(WA2f[mt], ahf, pe[mt]);   // logits (+const, invariant)
            v4f e;
            #pragma unroll
            for (int r = 0; r < 4; ++r) e[r] = __expf(pe[mt][r]);
            den[mt] += e;
            num[mt] += tfv * e;
            cmx[mt] = __builtin_elementwise_max(cmx[mt], tfv * gate);
        }
        xv_cur = xv_nxt;
    }

    // write out: lane owns channels mt*16 + 4q + r for its point n
    #pragma unroll
    for (int mt = 0; mt < 4; ++mt) {
        #pragma unroll
        for (int r = 0; r < 4; ++r) {
            const int ch = mt * 16 + 4 * q + r;
            out[((size_t)(b * 64 + ch)) * 8192 + n] =
                num[mt][r] / den[mt][r] + cmx[mt][r];
        }
    }
}

extern "C" void kernel_launch(void* const* d_in, const int* in_sizes, int n_in,
                              void* d_out, int out_size, void* d_ws, size_t ws_size,
                              hipStream_t stream) {
    const float* x       = (const float*)d_in[0];
    const float* trans_w = (const float*)d_in[1];
    const float* trans_g = (const float*)d_in[2];
    const float* trans_b = (const float*)d_in[3];
    const float* trans_m = (const float*)d_in[4];
    const float* trans_v = (const float*)d_in[5];
    const float* pos_w1  = (const float*)d_in[6];
    const float* pos_g   = (const float*)d_in[7];
    const float* pos_b   = (const float*)d_in[8];
    const float* pos_m   = (const float*)d_in[9];
    const float* pos_v   = (const float*)d_in[10];
    const float* pos_w2  = (const float*)d_in[11];
    const float* pos_b2  = (const float*)d_in[12];
    const float* gate_w1 = (const float*)d_in[13];
    const float* gate_g  = (const float*)d_in[14];
    const float* gate_b  = (const float*)d_in[15];
    const float* gate_m  = (const float*)d_in[16];
    const float* gate_v  = (const float*)d_in[17];
    const float* gate_w2 = (const float*)d_in[18];
    const float* gate_b2 = (const float*)d_in[19];
    const float* attn_w1 = (const float*)d_in[20];
    const float* attn_g  = (const float*)d_in[21];
    const float* attn_b  = (const float*)d_in[22];
    const float* attn_m  = (const float*)d_in[23];
    const float* attn_v  = (const float*)d_in[24];
    const float* attn_w2 = (const float*)d_in[25];
    const float* attn_b2 = (const float*)d_in[26];
    float* out = (float*)d_out;

    // 8 b * 128 blocks/b; block = 4 waves * 16 points
    gsl_mfma<<<1024, 256, 0, stream>>>(
        x, trans_w, trans_g, trans_b, trans_m, trans_v,
        pos_w1, pos_g, pos_b, pos_m, pos_v, pos_w2, pos_b2,
        gate_w1, gate_g, gate_b, gate_m, gate_v, gate_w2, gate_b2,
        attn_w1, attn_g, attn_b, attn_m, attn_v, attn_w2, attn_b2,
        out);
}

// Round 11
// 195.704 us; speedup vs baseline: 73.1189x; 1.0111x over previous
//
#include <hip/hip_runtime.h>
#include <math.h>

#define NEG 0.2f
#define EPSV 1e-5f

typedef _Float16 v8h __attribute__((ext_vector_type(8)));
typedef _Float16 v4h __attribute__((ext_vector_type(4)));
typedef _Float16 v2h __attribute__((ext_vector_type(2)));
typedef __fp16   f16x2 __attribute__((ext_vector_type(2)));
typedef float    v4f __attribute__((ext_vector_type(4)));

__device__ __forceinline__ float lrelu(float v) { return fmaxf(v, NEG * v); }
__device__ __forceinline__ v4f lrelu4(v4f v) {
    return __builtin_elementwise_max(v, v * NEG);
}
__device__ __forceinline__ v2h lreluh2(v2h v) {
    return __builtin_elementwise_max(v, v * (_Float16)NEG);
}

// cvt_pkrtz returns __fp16x2; bit-cast to _Float16x2 (same layout)
__device__ __forceinline__ v2h pk(float a, float b) {
    union { f16x2 i; v2h o; } u;
    u.i = __builtin_amdgcn_cvt_pkrtz(a, b);
    return u.o;
}

#define MFMA(a, b, c) __builtin_amdgcn_mfma_f32_16x16x32_f16((a), (b), (c), 0, 0, 0)

// MFMA mapping (verified round 6): wave owns 16 n (p = lane&15), loops k=0..19.
//   A-frag: A[m=lane&15][k=quad*8+i], B-frag: B[k=quad*8+i][n=lane&15]
//   C/D: col(point)=lane&15, row(ch)=quad*4+reg (+16*mtile)
// Round 11 = round 10 + NaN fix: AH B-frag tail read for q>=2 hit unwritten
// LDS (p=15,q>=2 reads past the 256-half written region; 0*NaN garbage = NaN).
// Since WA2f rows k>=16 are zero, q>=2 lanes now read 8*(q&1) — always
// written, finite, multiplied by zero. No init loop needed.
__global__ __launch_bounds__(256, 1)
void gsl_mfma(const float* __restrict__ x,
              const float* __restrict__ trans_w, const float* __restrict__ trans_g,
              const float* __restrict__ trans_b, const float* __restrict__ trans_m,
              const float* __restrict__ trans_v,
              const float* __restrict__ pos_w1, const float* __restrict__ pos_g,
              const float* __restrict__ pos_b, const float* __restrict__ pos_m,
              const float* __restrict__ pos_v, const float* __restrict__ pos_w2,
              const float* __restrict__ pos_b2,
              const float* __restrict__ gate_w1, const float* __restrict__ gate_g,
              const float* __restrict__ gate_b, const float* __restrict__ gate_m,
              const float* __restrict__ gate_v, const float* __restrict__ gate_w2,
              const float* __restrict__ gate_b2,
              const float* __restrict__ attn_w1, const float* __restrict__ attn_g,
              const float* __restrict__ attn_b, const float* __restrict__ attn_m,
              const float* __restrict__ attn_v, const float* __restrict__ attn_w2,
              const float* __restrict__ attn_b2,
              float* __restrict__ out)
{
    __shared__ _Float16 WH[3840];        // WP1 tiles(4*640) | WA1(640) | WG1(640)
    __shared__ float    PB2[64];
    __shared__ _Float16 PHB[4][2][1152]; // per-wave dbuf: 16 pts x stride 72
    __shared__ _Float16 AHB[4][2][288];  // per-wave dbuf: 16 pts x stride 16
    __shared__ _Float16 XSB[4][2560];    // per-wave x: [k][pt][c] 20x16x8

    const int tid  = threadIdx.x;
    const int wv   = tid >> 6;
    const int lane = tid & 63;
    const int p    = lane & 15;
    const int q    = lane >> 4;

    const int b  = blockIdx.x >> 7;
    const int n0 = ((blockIdx.x & 127) << 6) | (wv << 4);
    const int n  = n0 | p;

    // ---- stage x into XS (coalesced float4 reads, one-time scatter writes) ----
    {
        const float* xw = x + ((size_t)b * 6 * 8192 + n0) * 20;
        _Float16* XS = &XSB[wv][0];
        #pragma unroll
        for (int i = 0; i < 8; ++i) {
            int idx = i * 64 + lane;          // 480 float4 per wave
            if (idx < 480) {
                int c  = idx / 80;            // 80 float4 per channel
                int rm = idx - c * 80;
                int pt = rm / 5;
                int k0 = (rm - pt * 5) * 4;
                const float4 v = *(const float4*)(xw + (size_t)c * 163840 + pt * 20 + k0);
                _Float16* dst = XS + pt * 8 + c;
                dst[(k0 + 0) * 128] = (_Float16)v.x;
                dst[(k0 + 1) * 128] = (_Float16)v.y;
                dst[(k0 + 2) * 128] = (_Float16)v.z;
                dst[(k0 + 3) * 128] = (_Float16)v.w;
            }
        }
        #pragma unroll
        for (int i = 0; i < 5; ++i) {         // bias columns c=6 (1.0), c=7 (0)
            int idx = i * 64 + lane;          // 320 (k,pt) slots
            int k = idx >> 4, pt = idx & 15;
            *(v2h*)(XS + k * 128 + pt * 8 + 6) = (v2h){(_Float16)1.f, (_Float16)0.f};
        }
    }

    // ---- stage produce-side weights in block-shared LDS ----
    if (tid < 64) {
        const int c = tid;
        float sp = pos_g[c] * rsqrtf(pos_v[c] + EPSV);
        float bp = pos_b[c] - pos_m[c] * sp;
        _Float16* row = WH + (c >> 4) * 640 + (c & 15) * 40;
        for (int k = 0; k < 40; ++k) {
            float v = (k >= 3 && k < 6) ? pos_w1[c * 3 + (k - 3)] * sp
                                        : ((k == 6) ? bp : 0.f);
            row[k] = (_Float16)v;
        }
        PB2[c] = pos_b2[c];
    } else if (tid < 80) {
        const int j = tid - 64;
        float sa = attn_g[j] * rsqrtf(attn_v[j] + EPSV);
        float ba = attn_b[j] - attn_m[j] * sa;
        _Float16* row = WH + 2560 + j * 40;
        for (int k = 0; k < 40; ++k)
            row[k] = (_Float16)((k < 6) ? attn_w1[j * 6 + k] * sa
                                        : ((k == 6) ? ba : 0.f));
    } else if (tid < 96) {
        const int j = tid - 80;
        float sg = gate_g[j] * rsqrtf(gate_v[j] + EPSV);
        float bg = gate_b[j] - gate_m[j] * sg;
        _Float16* row = WH + 3200 + j * 40;
        for (int k = 0; k < 40; ++k)
            row[k] = (_Float16)((k < 6) ? gate_w1[j * 6 + k] * sg
                                        : ((k == 6) ? bg : 0.f));
    }

    // ---- persistent A-frags: W2f/WTf/WA2f in registers ----
    v8h W2f[4][2], WTf[4], WA2f[4];
    #pragma unroll
    for (int mt = 0; mt < 4; ++mt) {
        const int ch = mt * 16 + p;
        #pragma unroll
        for (int h = 0; h < 2; ++h)
            #pragma unroll
            for (int i = 0; i < 8; ++i)
                W2f[mt][h][i] = (_Float16)pos_w2[ch * 64 + h * 32 + q * 8 + i];
        #pragma unroll
        for (int i = 0; i < 8; ++i) {
            int k = q * 8 + i;
            WA2f[mt][i] = (k < 16) ? (_Float16)attn_w2[ch * 16 + k] : (_Float16)0.f;
        }
        float st = trans_g[ch] * rsqrtf(trans_v[ch] + EPSV);
        float bt = trans_b[ch] - trans_m[ch] * st;
        #pragma unroll
        for (int i = 0; i < 8; ++i) {
            int k = q * 8 + i;
            float v = (k < 6) ? trans_w[ch * 6 + k] * st : ((k == 6) ? bt : 0.f);
            WTf[mt][i] = (_Float16)v;
        }
    }
    float g2w[4];
    #pragma unroll
    for (int r = 0; r < 4; ++r) g2w[r] = gate_w2[4 * q + r];
    const float gb2v = gate_b2[0];

    __syncthreads();   // WH/PB2 visible to all waves

    const _Float16* const WP1p = WH + p * 40 + q * 8;          // + mt*640
    const _Float16* const WA1p = WH + 2560 + p * 40 + q * 8;
    const _Float16* const WG1p = WH + 3200 + p * 40 + q * 8;
    const float* const    PB2p = PB2 + 4 * q;                  // + mt*16
    const _Float16* const XS   = &XSB[wv][0];

    _Float16* const PHbase = &PHB[wv][0][0];
    _Float16* const AHbase = &AHB[wv][0][0];

    // q>=2 rows of WA2f are zero: read a written slot instead of the tail
    const int ahq = (q & 1) * 8;

    const v4f zero = {0.f, 0.f, 0.f, 0.f};
    v4f den[4], num[4], cmx[4];
    #pragma unroll
    for (int mt = 0; mt < 4; ++mt) {
        den[mt] = zero; num[mt] = zero;
        cmx[mt] = (v4f){-3.4e38f, -3.4e38f, -3.4e38f, -3.4e38f};
    }

    // ---- pipeline prologue: k=0 produce ----
    v8h xv_cur = *(const v8h*)(XS + p * 8);
    {
        v4f php[4];
        #pragma unroll
        for (int mt = 0; mt < 4; ++mt)
            php[mt] = MFMA(*(const v8h*)(WP1p + mt * 640), xv_cur, zero);
        v4f ahp = MFMA(*(const v8h*)WA1p, xv_cur, zero);
        _Float16* PHW = PHbase + p * 72 + 4 * q;
        #pragma unroll
        for (int mt = 0; mt < 4; ++mt) {
            union { v4h v; v2h h[2]; } u;
            u.h[0] = lreluh2(pk(php[mt][0], php[mt][1]));
            u.h[1] = lreluh2(pk(php[mt][2], php[mt][3]));
            *(v4h*)(PHW + mt * 16) = u.v;
        }
        union { v4h v; v2h h[2]; } ua;
        ua.h[0] = lreluh2(pk(ahp[0], ahp[1]));
        ua.h[1] = lreluh2(pk(ahp[2], ahp[3]));
        *(v4h*)(AHbase + p * 16 + 4 * q) = ua.v;
    }

    #pragma unroll 1
    for (int k = 0; k < 20; ++k) {
        const int sel = k & 1;
        // 1) issue reads for k (writes landed last iteration)
        _Float16* PH = PHbase + sel * 1152;
        _Float16* AH = AHbase + sel * 288;
        v8h phf0 = *(const v8h*)(PH + p * 72 + 8 * q);
        v8h phf1 = *(const v8h*)(PH + p * 72 + 32 + 8 * q);
        v8h ahf  = *(const v8h*)(AH + p * 16 + ahq);   // q>=2: dup of q&1 (A=0 there)

        // 2) produce(k+1) into the other buffer
        v8h xv_nxt = xv_cur;
        if (k < 19) {
            xv_nxt = *(const v8h*)(XS + (k + 1) * 128 + p * 8);
            v4f php[4];
            #pragma unroll
            for (int mt = 0; mt < 4; ++mt)
                php[mt] = MFMA(*(const v8h*)(WP1p + mt * 640), xv_nxt, zero);
            v4f ahp = MFMA(*(const v8h*)WA1p, xv_nxt, zero);
            _Float16* PHW = PHbase + (sel ^ 1) * 1152 + p * 72 + 4 * q;
            #pragma unroll
            for (int mt = 0; mt < 4; ++mt) {
                union { v4h v; v2h h[2]; } uu;
                uu.h[0] = lreluh2(pk(php[mt][0], php[mt][1]));
                uu.h[1] = lreluh2(pk(php[mt][2], php[mt][3]));
                *(v4h*)(PHW + mt * 16) = uu.v;
            }
            union { v4h v; v2h h[2]; } ua;
            ua.h[0] = lreluh2(pk(ahp[0], ahp[1]));
            ua.h[1] = lreluh2(pk(ahp[2], ahp[3]));
            *(v4h*)(AHbase + (sel ^ 1) * 288 + p * 16 + 4 * q) = ua.v;
        }

        // 3) consume(k): trans + gate from xv_cur
        v4f tfa[4];
        #pragma unroll
        for (int mt = 0; mt < 4; ++mt) tfa[mt] = MFMA(WTf[mt], xv_cur, zero);
        v4f ghp = MFMA(*(const v8h*)WG1p, xv_cur, zero);
        float ga = 0.f;
        #pragma unroll
        for (int r = 0; r < 4; ++r) ga += g2w[r] * lrelu(ghp[r]);
        ga += __shfl_xor(ga, 16);
        ga += __shfl_xor(ga, 32);
        const float gate = 1.f / (1.f + __expf(-(ga + gb2v)));

        // pe GEMM (C-init = pb2; constant shift softmax-invariant)
        v4f pe[4];
        #pragma unroll
        for (int mt = 0; mt < 4; ++mt) {
            pe[mt] = MFMA(W2f[mt][0], phf0, *(const v4f*)(PB2p + mt * 16));
            pe[mt] = MFMA(W2f[mt][1], phf1, pe[mt]);
        }

        #pragma unroll
        for (int mt = 0; mt < 4; ++mt) {
            v4f tfv = lrelu4(tfa[mt]) + pe[mt];
            pe[mt] = MFMA(WA2f[mt], ahf, pe[mt]);   // logits (+const, invariant)
            v4f e;
            #pragma unroll
            for (int r = 0; r < 4; ++r) e[r] = __expf(pe[mt][r]);
            den[mt] += e;
            num[mt] += tfv * e;
            cmx[mt] = __builtin_elementwise_max(cmx[mt], tfv * gate);
        }
        xv_cur = xv_nxt;
    }

    // write out: lane owns channels mt*16 + 4q + r for its point n
    #pragma unroll
    for (int mt = 0; mt < 4; ++mt) {
        #pragma unroll
        for (int r = 0; r < 4; ++r) {
            const int ch = mt * 16 + 4 * q + r;
            out[((size_t)(b * 64 + ch)) * 8192 + n] =
                num[mt][r] / den[mt][r] + cmx[mt][r];
        }
    }
}

extern "C" void kernel_launch(void* const* d_in, const int* in_sizes, int n_in,
                              void* d_out, int out_size, void* d_ws, size_t ws_size,
                              hipStream_t stream) {
    const float* x       = (const float*)d_in[0];
    const float* trans_w = (const float*)d_in[1];
    const float* trans_g = (const float*)d_in[2];
    const float* trans_b = (const float*)d_in[3];
    const float* trans_m = (const float*)d_in[4];
    const float* trans_v = (const float*)d_in[5];
    const float* pos_w1  = (const float*)d_in[6];
    const float* pos_g   = (const float*)d_in[7];
    const float* pos_b   = (const float*)d_in[8];
    const float* pos_m   = (const float*)d_in[9];
    const float* pos_v   = (const float*)d_in[10];
    const float* pos_w2  = (const float*)d_in[11];
    const float* pos_b2  = (const float*)d_in[12];
    const float* gate_w1 = (const float*)d_in[13];
    const float* gate_g  = (const float*)d_in[14];
    const float* gate_b  = (const float*)d_in[15];
    const float* gate_m  = (const float*)d_in[16];
    const float* gate_v  = (const float*)d_in[17];
    const float* gate_w2 = (const float*)d_in[18];
    const float* gate_b2 = (const float*)d_in[19];
    const float* attn_w1 = (const float*)d_in[20];
    const float* attn_g  = (const float*)d_in[21];
    const float* attn_b  = (const float*)d_in[22];
    const float* attn_m  = (const float*)d_in[23];
    const float* attn_v  = (const float*)d_in[24];
    const float* attn_w2 = (const float*)d_in[25];
    const float* attn_b2 = (const float*)d_in[26];
    float* out = (float*)d_out;

    // 8 b * 128 blocks/b; block = 4 waves * 16 points
    gsl_mfma<<<1024, 256, 0, stream>>>(
        x, trans_w, trans_g, trans_b, trans_m, trans_v,
        pos_w1, pos_g, pos_b, pos_m, pos_v, pos_w2, pos_b2,
        gate_w1, gate_g, gate_b, gate_m, gate_v, gate_w2, gate_b2,
        attn_w1, attn_g, attn_b, attn_m, attn_v, attn_w2, attn_b2,
        out);
}

// Round 12
// 187.863 us; speedup vs baseline: 76.1706x; 1.0417x over previous
//
#include <hip/hip_runtime.h>
#include <math.h>

#define NEG 0.2f
#define EPSV 1e-5f

typedef _Float16 v8h __attribute__((ext_vector_type(8)));
typedef _Float16 v4h __attribute__((ext_vector_type(4)));
typedef _Float16 v2h __attribute__((ext_vector_type(2)));
typedef __fp16   f16x2 __attribute__((ext_vector_type(2)));
typedef float    v4f __attribute__((ext_vector_type(4)));

__device__ __forceinline__ float lrelu(float v) { return fmaxf(v, NEG * v); }
__device__ __forceinline__ v4f lrelu4(v4f v) {
    return __builtin_elementwise_max(v, v * NEG);
}
__device__ __forceinline__ v2h lreluh2(v2h v) {
    return __builtin_elementwise_max(v, v * (_Float16)NEG);
}

// cvt_pkrtz returns __fp16x2; bit-cast to _Float16x2 (same layout)
__device__ __forceinline__ v2h pk(float a, float b) {
    union { f16x2 i; v2h o; } u;
    u.i = __builtin_amdgcn_cvt_pkrtz(a, b);
    return u.o;
}

#define MFMA32(a, b, c) __builtin_amdgcn_mfma_f32_16x16x32_f16((a), (b), (c), 0, 0, 0)
#define MFMA16(a, b, c) __builtin_amdgcn_mfma_f32_16x16x16f16((a), (b), (c), 0, 0, 0)

// Round 12: R6-R11 invariant = 19% occupancy (2 waves/SIMD, ~172 total regs,
// just over the 512/3=170 3-wave boundary). Cut frag registers by moving all
// K<=16 GEMMs (trans, logits, produce convs) from 16x16x32 (4-VGPR frags) to
// v_mfma_f32_16x16x16_f16 (2-VGPR frags): A[m=lane&15][k=q*4+i],
// B[k=q*4+i][n=lane&15], C/D col=lane&15 row=q*4+reg (same as verified).
// pe GEMM stays 16x16x32 (K=64 full). AH rows = exactly 16 halves (stride 20,
// read==write addr, all lanes real data). xv B-frag q>=2 reads written slot
// (A-side k>=8 zero).
__global__ __launch_bounds__(256, 1)
void gsl_mfma(const float* __restrict__ x,
              const float* __restrict__ trans_w, const float* __restrict__ trans_g,
              const float* __restrict__ trans_b, const float* __restrict__ trans_m,
              const float* __restrict__ trans_v,
              const float* __restrict__ pos_w1, const float* __restrict__ pos_g,
              const float* __restrict__ pos_b, const float* __restrict__ pos_m,
              const float* __restrict__ pos_v, const float* __restrict__ pos_w2,
              const float* __restrict__ pos_b2,
              const float* __restrict__ gate_w1, const float* __restrict__ gate_g,
              const float* __restrict__ gate_b, const float* __restrict__ gate_m,
              const float* __restrict__ gate_v, const float* __restrict__ gate_w2,
              const float* __restrict__ gate_b2,
              const float* __restrict__ attn_w1, const float* __restrict__ attn_g,
              const float* __restrict__ attn_b, const float* __restrict__ attn_m,
              const float* __restrict__ attn_v, const float* __restrict__ attn_w2,
              const float* __restrict__ attn_b2,
              float* __restrict__ out)
{
    __shared__ _Float16 WH[1920];        // WP1 4x(16x20) | WA1 16x20 | WG1 16x20
    __shared__ float    PB2[64];
    __shared__ _Float16 PHB[4][2][1152]; // per-wave dbuf: 16 pts x stride 72
    __shared__ _Float16 AHB[4][2][320];  // per-wave dbuf: 16 pts x stride 20
    __shared__ _Float16 XSB[4][2560];    // per-wave x: [k][pt][c] 20x16x8

    const int tid  = threadIdx.x;
    const int wv   = tid >> 6;
    const int lane = tid & 63;
    const int p    = lane & 15;
    const int q    = lane >> 4;

    const int b  = blockIdx.x >> 7;
    const int n0 = ((blockIdx.x & 127) << 6) | (wv << 4);
    const int n  = n0 | p;

    // ---- stage x into XS (coalesced float4 reads, one-time scatter writes) ----
    {
        const float* xw = x + ((size_t)b * 6 * 8192 + n0) * 20;
        _Float16* XS = &XSB[wv][0];
        #pragma unroll
        for (int i = 0; i < 8; ++i) {
            int idx = i * 64 + lane;          // 480 float4 per wave
            if (idx < 480) {
                int c  = idx / 80;            // 80 float4 per channel
                int rm = idx - c * 80;
                int pt = rm / 5;
                int k0 = (rm - pt * 5) * 4;
                const float4 v = *(const float4*)(xw + (size_t)c * 163840 + pt * 20 + k0);
                _Float16* dst = XS + pt * 8 + c;
                dst[(k0 + 0) * 128] = (_Float16)v.x;
                dst[(k0 + 1) * 128] = (_Float16)v.y;
                dst[(k0 + 2) * 128] = (_Float16)v.z;
                dst[(k0 + 3) * 128] = (_Float16)v.w;
            }
        }
        #pragma unroll
        for (int i = 0; i < 5; ++i) {         // bias columns c=6 (1.0), c=7 (0)
            int idx = i * 64 + lane;          // 320 (k,pt) slots
            int k = idx >> 4, pt = idx & 15;
            *(v2h*)(XS + k * 128 + pt * 8 + 6) = (v2h){(_Float16)1.f, (_Float16)0.f};
        }
    }

    // ---- stage produce-side weights in block-shared LDS (rows stride 20h) ----
    if (tid < 64) {
        const int c = tid;
        float sp = pos_g[c] * rsqrtf(pos_v[c] + EPSV);
        float bp = pos_b[c] - pos_m[c] * sp;
        _Float16* row = WH + (c >> 4) * 320 + (c & 15) * 20;
        for (int k = 0; k < 20; ++k) {
            float v = (k >= 3 && k < 6) ? pos_w1[c * 3 + (k - 3)] * sp
                                        : ((k == 6) ? bp : 0.f);
            row[k] = (_Float16)v;
        }
        PB2[c] = pos_b2[c];
    } else if (tid < 80) {
        const int j = tid - 64;
        float sa = attn_g[j] * rsqrtf(attn_v[j] + EPSV);
        float ba = attn_b[j] - attn_m[j] * sa;
        _Float16* row = WH + 1280 + j * 20;
        for (int k = 0; k < 20; ++k)
            row[k] = (_Float16)((k < 6) ? attn_w1[j * 6 + k] * sa
                                        : ((k == 6) ? ba : 0.f));
    } else if (tid < 96) {
        const int j = tid - 80;
        float sg = gate_g[j] * rsqrtf(gate_v[j] + EPSV);
        float bg = gate_b[j] - gate_m[j] * sg;
        _Float16* row = WH + 1600 + j * 20;
        for (int k = 0; k < 20; ++k)
            row[k] = (_Float16)((k < 6) ? gate_w1[j * 6 + k] * sg
                                        : ((k == 6) ? bg : 0.f));
    }

    // ---- persistent A-frags: W2f (K=64, x32 shape), WTf/WA2f (K=16, x16) ----
    v8h W2f[4][2];
    v4h WTf[4], WA2f[4];
    #pragma unroll
    for (int mt = 0; mt < 4; ++mt) {
        const int ch = mt * 16 + p;
        #pragma unroll
        for (int h = 0; h < 2; ++h)
            #pragma unroll
            for (int i = 0; i < 8; ++i)
                W2f[mt][h][i] = (_Float16)pos_w2[ch * 64 + h * 32 + q * 8 + i];
        #pragma unroll
        for (int i = 0; i < 4; ++i)
            WA2f[mt][i] = (_Float16)attn_w2[ch * 16 + q * 4 + i];
        float st = trans_g[ch] * rsqrtf(trans_v[ch] + EPSV);
        float bt = trans_b[ch] - trans_m[ch] * st;
        #pragma unroll
        for (int i = 0; i < 4; ++i) {
            int k = q * 4 + i;
            float v = (k < 6) ? trans_w[ch * 6 + k] * st : ((k == 6) ? bt : 0.f);
            WTf[mt][i] = (_Float16)v;
        }
    }
    float g2w[4];
    #pragma unroll
    for (int r = 0; r < 4; ++r) g2w[r] = gate_w2[4 * q + r];
    const float gb2v = gate_b2[0];

    __syncthreads();   // WH/PB2 visible to all waves

    const _Float16* const WP1p = WH + p * 20 + q * 4;          // + mt*320
    const _Float16* const WA1p = WH + 1280 + p * 20 + q * 4;
    const _Float16* const WG1p = WH + 1600 + p * 20 + q * 4;
    const float* const    PB2p = PB2 + 4 * q;                  // + mt*16
    const _Float16* const XS   = &XSB[wv][0];

    _Float16* const PHbase = &PHB[wv][0][0];
    _Float16* const AHbase = &AHB[wv][0][0];

    const int xoff = p * 8 + (q & 1) * 4;   // q>=2: dup of q&1 (A-side k>=8 zero)

    const v4f zero = {0.f, 0.f, 0.f, 0.f};
    v4f den[4], num[4], cmx[4];
    #pragma unroll
    for (int mt = 0; mt < 4; ++mt) {
        den[mt] = zero; num[mt] = zero;
        cmx[mt] = (v4f){-3.4e38f, -3.4e38f, -3.4e38f, -3.4e38f};
    }

    // ---- pipeline prologue: k=0 produce ----
    v4h xv_cur = *(const v4h*)(XS + xoff);
    {
        v4f php[4];
        #pragma unroll
        for (int mt = 0; mt < 4; ++mt)
            php[mt] = MFMA16(*(const v4h*)(WP1p + mt * 320), xv_cur, zero);
        v4f ahp = MFMA16(*(const v4h*)WA1p, xv_cur, zero);
        _Float16* PHW = PHbase + p * 72 + 4 * q;
        #pragma unroll
        for (int mt = 0; mt < 4; ++mt) {
            union { v4h v; v2h h[2]; } u;
            u.h[0] = lreluh2(pk(php[mt][0], php[mt][1]));
            u.h[1] = lreluh2(pk(php[mt][2], php[mt][3]));
            *(v4h*)(PHW + mt * 16) = u.v;
        }
        union { v4h v; v2h h[2]; } ua;
        ua.h[0] = lreluh2(pk(ahp[0], ahp[1]));
        ua.h[1] = lreluh2(pk(ahp[2], ahp[3]));
        *(v4h*)(AHbase + p * 20 + 4 * q) = ua.v;
    }

    #pragma unroll 1
    for (int k = 0; k < 20; ++k) {
        const int sel = k & 1;
        // 1) issue reads for k (writes landed last iteration)
        _Float16* PH = PHbase + sel * 1152;
        _Float16* AH = AHbase + sel * 320;
        v8h phf0 = *(const v8h*)(PH + p * 72 + 8 * q);
        v8h phf1 = *(const v8h*)(PH + p * 72 + 32 + 8 * q);
        v4h ahf  = *(const v4h*)(AH + p * 20 + 4 * q);  // read == write addr

        // 2) produce(k+1) into the other buffer
        v4h xv_nxt = xv_cur;
        if (k < 19) {
            xv_nxt = *(const v4h*)(XS + (k + 1) * 128 + xoff);
            v4f php[4];
            #pragma unroll
            for (int mt = 0; mt < 4; ++mt)
                php[mt] = MFMA16(*(const v4h*)(WP1p + mt * 320), xv_nxt, zero);
            v4f ahp = MFMA16(*(const v4h*)WA1p, xv_nxt, zero);
            _Float16* PHW = PHbase + (sel ^ 1) * 1152 + p * 72 + 4 * q;
            #pragma unroll
            for (int mt = 0; mt < 4; ++mt) {
                union { v4h v; v2h h[2]; } uu;
                uu.h[0] = lreluh2(pk(php[mt][0], php[mt][1]));
                uu.h[1] = lreluh2(pk(php[mt][2], php[mt][3]));
                *(v4h*)(PHW + mt * 16) = uu.v;
            }
            union { v4h v; v2h h[2]; } ua;
            ua.h[0] = lreluh2(pk(ahp[0], ahp[1]));
            ua.h[1] = lreluh2(pk(ahp[2], ahp[3]));
            *(v4h*)(AHbase + (sel ^ 1) * 320 + p * 20 + 4 * q) = ua.v;
        }

        // 3) consume(k): trans + gate from xv_cur (K=16 MFMAs)
        v4f tfa[4];
        #pragma unroll
        for (int mt = 0; mt < 4; ++mt) tfa[mt] = MFMA16(WTf[mt], xv_cur, zero);
        v4f ghp = MFMA16(*(const v4h*)WG1p, xv_cur, zero);
        float ga = 0.f;
        #pragma unroll
        for (int r = 0; r < 4; ++r) ga += g2w[r] * lrelu(ghp[r]);
        ga += __shfl_xor(ga, 16);
        ga += __shfl_xor(ga, 32);
        const float gate = 1.f / (1.f + __expf(-(ga + gb2v)));

        // pe GEMM (K=64, x32 shape; C-init = pb2, softmax-invariant shift)
        v4f pe[4];
        #pragma unroll
        for (int mt = 0; mt < 4; ++mt) {
            pe[mt] = MFMA32(W2f[mt][0], phf0, *(const v4f*)(PB2p + mt * 16));
            pe[mt] = MFMA32(W2f[mt][1], phf1, pe[mt]);
        }

        #pragma unroll
        for (int mt = 0; mt < 4; ++mt) {
            v4f tfv = lrelu4(tfa[mt]) + pe[mt];
            pe[mt] = MFMA16(WA2f[mt], ahf, pe[mt]);   // logits (K=16)
            v4f e;
            #pragma unroll
            for (int r = 0; r < 4; ++r) e[r] = __expf(pe[mt][r]);
            den[mt] += e;
            num[mt] += tfv * e;
            cmx[mt] = __builtin_elementwise_max(cmx[mt], tfv * gate);
        }
        xv_cur = xv_nxt;
    }

    // write out: lane owns channels mt*16 + 4q + r for its point n
    #pragma unroll
    for (int mt = 0; mt < 4; ++mt) {
        #pragma unroll
        for (int r = 0; r < 4; ++r) {
            const int ch = mt * 16 + 4 * q + r;
            out[((size_t)(b * 64 + ch)) * 8192 + n] =
                num[mt][r] / den[mt][r] + cmx[mt][r];
        }
    }
}

extern "C" void kernel_launch(void* const* d_in, const int* in_sizes, int n_in,
                              void* d_out, int out_size, void* d_ws, size_t ws_size,
                              hipStream_t stream) {
    const float* x       = (const float*)d_in[0];
    const float* trans_w = (const float*)d_in[1];
    const float* trans_g = (const float*)d_in[2];
    const float* trans_b = (const float*)d_in[3];
    const float* trans_m = (const float*)d_in[4];
    const float* trans_v = (const float*)d_in[5];
    const float* pos_w1  = (const float*)d_in[6];
    const float* pos_g   = (const float*)d_in[7];
    const float* pos_b   = (const float*)d_in[8];
    const float* pos_m   = (const float*)d_in[9];
    const float* pos_v   = (const float*)d_in[10];
    const float* pos_w2  = (const float*)d_in[11];
    const float* pos_b2  = (const float*)d_in[12];
    const float* gate_w1 = (const float*)d_in[13];
    const float* gate_g  = (const float*)d_in[14];
    const float* gate_b  = (const float*)d_in[15];
    const float* gate_m  = (const float*)d_in[16];
    const float* gate_v  = (const float*)d_in[17];
    const float* gate_w2 = (const float*)d_in[18];
    const float* gate_b2 = (const float*)d_in[19];
    const float* attn_w1 = (const float*)d_in[20];
    const float* attn_g  = (const float*)d_in[21];
    const float* attn_b  = (const float*)d_in[22];
    const float* attn_m  = (const float*)d_in[23];
    const float* attn_v  = (const float*)d_in[24];
    const float* attn_w2 = (const float*)d_in[25];
    const float* attn_b2 = (const float*)d_in[26];
    float* out = (float*)d_out;

    // 8 b * 128 blocks/b; block = 4 waves * 16 points
    gsl_mfma<<<1024, 256, 0, stream>>>(
        x, trans_w, trans_g, trans_b, trans_m, trans_v,
        pos_w1, pos_g, pos_b, pos_m, pos_v, pos_w2, pos_b2,
        gate_w1, gate_g, gate_b, gate_m, gate_v, gate_w2, gate_b2,
        attn_w1, attn_g, attn_b, attn_m, attn_v, attn_w2, attn_b2,
        out);
}

// Round 13
// 180.371 us; speedup vs baseline: 79.3347x; 1.0415x over previous
//
#include <hip/hip_runtime.h>
#include <math.h>

#define NEG 0.2f
#define EPSV 1e-5f

typedef _Float16 v8h __attribute__((ext_vector_type(8)));
typedef _Float16 v4h __attribute__((ext_vector_type(4)));
typedef _Float16 v2h __attribute__((ext_vector_type(2)));
typedef __fp16   f16x2 __attribute__((ext_vector_type(2)));
typedef float    v4f __attribute__((ext_vector_type(4)));

__device__ __forceinline__ float lrelu(float v) { return fmaxf(v, NEG * v); }
__device__ __forceinline__ v4f lrelu4(v4f v) {
    return __builtin_elementwise_max(v, v * NEG);
}
__device__ __forceinline__ v2h lreluh2(v2h v) {
    return __builtin_elementwise_max(v, v * (_Float16)NEG);
}

// cvt_pkrtz returns __fp16x2; bit-cast to _Float16x2 (same layout)
__device__ __forceinline__ v2h pk(float a, float b) {
    union { f16x2 i; v2h o; } u;
    u.i = __builtin_amdgcn_cvt_pkrtz(a, b);
    return u.o;
}

#define MFMA32(a, b, c) __builtin_amdgcn_mfma_f32_16x16x32_f16((a), (b), (c), 0, 0, 0)
#define MFMA16(a, b, c) __builtin_amdgcn_mfma_f32_16x16x16f16((a), (b), (c), 0, 0, 0)

// Round 13: R12 analysis — VALU busy time (48us) is AT the packed-f32 work
// floor; all remaining gap is 39% idle at 2 waves/SIMD. Changes:
// (1) __launch_bounds__(256,3): force allocator to a 3-waves/EU (~170 reg
//     total) budget — (256,1) gave it no incentive to squeeze below 2-wave.
// (2) per-mt streaming consume: pe[4]/tfa[4] (32 live regs) -> per-mt temps
//     (~8 live), so the 170 budget holds without scratch spills.
__global__ __launch_bounds__(256, 3)
void gsl_mfma(const float* __restrict__ x,
              const float* __restrict__ trans_w, const float* __restrict__ trans_g,
              const float* __restrict__ trans_b, const float* __restrict__ trans_m,
              const float* __restrict__ trans_v,
              const float* __restrict__ pos_w1, const float* __restrict__ pos_g,
              const float* __restrict__ pos_b, const float* __restrict__ pos_m,
              const float* __restrict__ pos_v, const float* __restrict__ pos_w2,
              const float* __restrict__ pos_b2,
              const float* __restrict__ gate_w1, const float* __restrict__ gate_g,
              const float* __restrict__ gate_b, const float* __restrict__ gate_m,
              const float* __restrict__ gate_v, const float* __restrict__ gate_w2,
              const float* __restrict__ gate_b2,
              const float* __restrict__ attn_w1, const float* __restrict__ attn_g,
              const float* __restrict__ attn_b, const float* __restrict__ attn_m,
              const float* __restrict__ attn_v, const float* __restrict__ attn_w2,
              const float* __restrict__ attn_b2,
              float* __restrict__ out)
{
    __shared__ _Float16 WH[1920];        // WP1 4x(16x20) | WA1 16x20 | WG1 16x20
    __shared__ float    PB2[64];
    __shared__ _Float16 PHB[4][2][1152]; // per-wave dbuf: 16 pts x stride 72
    __shared__ _Float16 AHB[4][2][320];  // per-wave dbuf: 16 pts x stride 20
    __shared__ _Float16 XSB[4][2560];    // per-wave x: [k][pt][c] 20x16x8

    const int tid  = threadIdx.x;
    const int wv   = tid >> 6;
    const int lane = tid & 63;
    const int p    = lane & 15;
    const int q    = lane >> 4;

    const int b  = blockIdx.x >> 7;
    const int n0 = ((blockIdx.x & 127) << 6) | (wv << 4);
    const int n  = n0 | p;

    // ---- stage x into XS (coalesced float4 reads, one-time scatter writes) ----
    {
        const float* xw = x + ((size_t)b * 6 * 8192 + n0) * 20;
        _Float16* XS = &XSB[wv][0];
        #pragma unroll
        for (int i = 0; i < 8; ++i) {
            int idx = i * 64 + lane;          // 480 float4 per wave
            if (idx < 480) {
                int c  = idx / 80;            // 80 float4 per channel
                int rm = idx - c * 80;
                int pt = rm / 5;
                int k0 = (rm - pt * 5) * 4;
                const float4 v = *(const float4*)(xw + (size_t)c * 163840 + pt * 20 + k0);
                _Float16* dst = XS + pt * 8 + c;
                dst[(k0 + 0) * 128] = (_Float16)v.x;
                dst[(k0 + 1) * 128] = (_Float16)v.y;
                dst[(k0 + 2) * 128] = (_Float16)v.z;
                dst[(k0 + 3) * 128] = (_Float16)v.w;
            }
        }
        #pragma unroll
        for (int i = 0; i < 5; ++i) {         // bias columns c=6 (1.0), c=7 (0)
            int idx = i * 64 + lane;          // 320 (k,pt) slots
            int k = idx >> 4, pt = idx & 15;
            *(v2h*)(XS + k * 128 + pt * 8 + 6) = (v2h){(_Float16)1.f, (_Float16)0.f};
        }
    }

    // ---- stage produce-side weights in block-shared LDS (rows stride 20h) ----
    if (tid < 64) {
        const int c = tid;
        float sp = pos_g[c] * rsqrtf(pos_v[c] + EPSV);
        float bp = pos_b[c] - pos_m[c] * sp;
        _Float16* row = WH + (c >> 4) * 320 + (c & 15) * 20;
        for (int k = 0; k < 20; ++k) {
            float v = (k >= 3 && k < 6) ? pos_w1[c * 3 + (k - 3)] * sp
                                        : ((k == 6) ? bp : 0.f);
            row[k] = (_Float16)v;
        }
        PB2[c] = pos_b2[c];
    } else if (tid < 80) {
        const int j = tid - 64;
        float sa = attn_g[j] * rsqrtf(attn_v[j] + EPSV);
        float ba = attn_b[j] - attn_m[j] * sa;
        _Float16* row = WH + 1280 + j * 20;
        for (int k = 0; k < 20; ++k)
            row[k] = (_Float16)((k < 6) ? attn_w1[j * 6 + k] * sa
                                        : ((k == 6) ? ba : 0.f));
    } else if (tid < 96) {
        const int j = tid - 80;
        float sg = gate_g[j] * rsqrtf(gate_v[j] + EPSV);
        float bg = gate_b[j] - gate_m[j] * sg;
        _Float16* row = WH + 1600 + j * 20;
        for (int k = 0; k < 20; ++k)
            row[k] = (_Float16)((k < 6) ? gate_w1[j * 6 + k] * sg
                                        : ((k == 6) ? bg : 0.f));
    }

    // ---- persistent A-frags: W2f (K=64, x32 shape), WTf/WA2f (K=16, x16) ----
    v8h W2f[4][2];
    v4h WTf[4], WA2f[4];
    #pragma unroll
    for (int mt = 0; mt < 4; ++mt) {
        const int ch = mt * 16 + p;
        #pragma unroll
        for (int h = 0; h < 2; ++h)
            #pragma unroll
            for (int i = 0; i < 8; ++i)
                W2f[mt][h][i] = (_Float16)pos_w2[ch * 64 + h * 32 + q * 8 + i];
        #pragma unroll
        for (int i = 0; i < 4; ++i)
            WA2f[mt][i] = (_Float16)attn_w2[ch * 16 + q * 4 + i];
        float st = trans_g[ch] * rsqrtf(trans_v[ch] + EPSV);
        float bt = trans_b[ch] - trans_m[ch] * st;
        #pragma unroll
        for (int i = 0; i < 4; ++i) {
            int k = q * 4 + i;
            float v = (k < 6) ? trans_w[ch * 6 + k] * st : ((k == 6) ? bt : 0.f);
            WTf[mt][i] = (_Float16)v;
        }
    }
    float g2w[4];
    #pragma unroll
    for (int r = 0; r < 4; ++r) g2w[r] = gate_w2[4 * q + r];
    const float gb2v = gate_b2[0];

    __syncthreads();   // WH/PB2 visible to all waves

    const _Float16* const WP1p = WH + p * 20 + q * 4;          // + mt*320
    const _Float16* const WA1p = WH + 1280 + p * 20 + q * 4;
    const _Float16* const WG1p = WH + 1600 + p * 20 + q * 4;
    const float* const    PB2p = PB2 + 4 * q;                  // + mt*16
    const _Float16* const XS   = &XSB[wv][0];

    _Float16* const PHbase = &PHB[wv][0][0];
    _Float16* const AHbase = &AHB[wv][0][0];

    const int xoff = p * 8 + (q & 1) * 4;   // q>=2: dup of q&1 (A-side k>=8 zero)

    const v4f zero = {0.f, 0.f, 0.f, 0.f};
    v4f den[4], num[4], cmx[4];
    #pragma unroll
    for (int mt = 0; mt < 4; ++mt) {
        den[mt] = zero; num[mt] = zero;
        cmx[mt] = (v4f){-3.4e38f, -3.4e38f, -3.4e38f, -3.4e38f};
    }

    // ---- pipeline prologue: k=0 produce ----
    v4h xv_cur = *(const v4h*)(XS + xoff);
    {
        v4f php[4];
        #pragma unroll
        for (int mt = 0; mt < 4; ++mt)
            php[mt] = MFMA16(*(const v4h*)(WP1p + mt * 320), xv_cur, zero);
        v4f ahp = MFMA16(*(const v4h*)WA1p, xv_cur, zero);
        _Float16* PHW = PHbase + p * 72 + 4 * q;
        #pragma unroll
        for (int mt = 0; mt < 4; ++mt) {
            union { v4h v; v2h h[2]; } u;
            u.h[0] = lreluh2(pk(php[mt][0], php[mt][1]));
            u.h[1] = lreluh2(pk(php[mt][2], php[mt][3]));
            *(v4h*)(PHW + mt * 16) = u.v;
        }
        union { v4h v; v2h h[2]; } ua;
        ua.h[0] = lreluh2(pk(ahp[0], ahp[1]));
        ua.h[1] = lreluh2(pk(ahp[2], ahp[3]));
        *(v4h*)(AHbase + p * 20 + 4 * q) = ua.v;
    }

    #pragma unroll 1
    for (int k = 0; k < 20; ++k) {
        const int sel = k & 1;
        // 1) issue reads for k (writes landed last iteration)
        _Float16* PH = PHbase + sel * 1152;
        _Float16* AH = AHbase + sel * 320;
        v8h phf0 = *(const v8h*)(PH + p * 72 + 8 * q);
        v8h phf1 = *(const v8h*)(PH + p * 72 + 32 + 8 * q);
        v4h ahf  = *(const v4h*)(AH + p * 20 + 4 * q);  // read == write addr

        // 2) produce(k+1) into the other buffer
        v4h xv_nxt = xv_cur;
        if (k < 19) {
            xv_nxt = *(const v4h*)(XS + (k + 1) * 128 + xoff);
            v4f php[4];
            #pragma unroll
            for (int mt = 0; mt < 4; ++mt)
                php[mt] = MFMA16(*(const v4h*)(WP1p + mt * 320), xv_nxt, zero);
            v4f ahp = MFMA16(*(const v4h*)WA1p, xv_nxt, zero);
            _Float16* PHW = PHbase + (sel ^ 1) * 1152 + p * 72 + 4 * q;
            #pragma unroll
            for (int mt = 0; mt < 4; ++mt) {
                union { v4h v; v2h h[2]; } uu;
                uu.h[0] = lreluh2(pk(php[mt][0], php[mt][1]));
                uu.h[1] = lreluh2(pk(php[mt][2], php[mt][3]));
                *(v4h*)(PHW + mt * 16) = uu.v;
            }
            union { v4h v; v2h h[2]; } ua;
            ua.h[0] = lreluh2(pk(ahp[0], ahp[1]));
            ua.h[1] = lreluh2(pk(ahp[2], ahp[3]));
            *(v4h*)(AHbase + (sel ^ 1) * 320 + p * 20 + 4 * q) = ua.v;
        }

        // 3) consume(k): gate first (needed by every mt's cmx)
        v4f ghp = MFMA16(*(const v4h*)WG1p, xv_cur, zero);
        float ga = 0.f;
        #pragma unroll
        for (int r = 0; r < 4; ++r) ga += g2w[r] * lrelu(ghp[r]);
        ga += __shfl_xor(ga, 16);
        ga += __shfl_xor(ga, 32);
        const float gate = 1.f / (1.f + __expf(-(ga + gb2v)));

        // per-mt streaming: only one mt's temporaries live at a time
        #pragma unroll
        for (int mt = 0; mt < 4; ++mt) {
            v4f pe = MFMA32(W2f[mt][0], phf0, *(const v4f*)(PB2p + mt * 16));
            pe = MFMA32(W2f[mt][1], phf1, pe);
            v4f tfa = MFMA16(WTf[mt], xv_cur, zero);
            v4f tfv = lrelu4(tfa) + pe;
            pe = MFMA16(WA2f[mt], ahf, pe);   // logits (K=16)
            v4f e;
            #pragma unroll
            for (int r = 0; r < 4; ++r) e[r] = __expf(pe[r]);
            den[mt] += e;
            num[mt] += tfv * e;
            cmx[mt] = __builtin_elementwise_max(cmx[mt], tfv * gate);
        }
        xv_cur = xv_nxt;
    }

    // write out: lane owns channels mt*16 + 4q + r for its point n
    #pragma unroll
    for (int mt = 0; mt < 4; ++mt) {
        #pragma unroll
        for (int r = 0; r < 4; ++r) {
            const int ch = mt * 16 + 4 * q + r;
            out[((size_t)(b * 64 + ch)) * 8192 + n] =
                num[mt][r] / den[mt][r] + cmx[mt][r];
        }
    }
}

extern "C" void kernel_launch(void* const* d_in, const int* in_sizes, int n_in,
                              void* d_out, int out_size, void* d_ws, size_t ws_size,
                              hipStream_t stream) {
    const float* x       = (const float*)d_in[0];
    const float* trans_w = (const float*)d_in[1];
    const float* trans_g = (const float*)d_in[2];
    const float* trans_b = (const float*)d_in[3];
    const float* trans_m = (const float*)d_in[4];
    const float* trans_v = (const float*)d_in[5];
    const float* pos_w1  = (const float*)d_in[6];
    const float* pos_g   = (const float*)d_in[7];
    const float* pos_b   = (const float*)d_in[8];
    const float* pos_m   = (const float*)d_in[9];
    const float* pos_v   = (const float*)d_in[10];
    const float* pos_w2  = (const float*)d_in[11];
    const float* pos_b2  = (const float*)d_in[12];
    const float* gate_w1 = (const float*)d_in[13];
    const float* gate_g  = (const float*)d_in[14];
    const float* gate_b  = (const float*)d_in[15];
    const float* gate_m  = (const float*)d_in[16];
    const float* gate_v  = (const float*)d_in[17];
    const float* gate_w2 = (const float*)d_in[18];
    const float* gate_b2 = (const float*)d_in[19];
    const float* attn_w1 = (const float*)d_in[20];
    const float* attn_g  = (const float*)d_in[21];
    const float* attn_b  = (const float*)d_in[22];
    const float* attn_m  = (const float*)d_in[23];
    const float* attn_v  = (const float*)d_in[24];
    const float* attn_w2 = (const float*)d_in[25];
    const float* attn_b2 = (const float*)d_in[26];
    float* out = (float*)d_out;

    // 8 b * 128 blocks/b; block = 4 waves * 16 points
    gsl_mfma<<<1024, 256, 0, stream>>>(
        x, trans_w, trans_g, trans_b, trans_m, trans_v,
        pos_w1, pos_g, pos_b, pos_m, pos_v, pos_w2, pos_b2,
        gate_w1, gate_g, gate_b, gate_m, gate_v, gate_w2, gate_b2,
        attn_w1, attn_g, attn_b, attn_m, attn_v, attn_w2, attn_b2,
        out);
}

// Round 14
// 177.043 us; speedup vs baseline: 80.8261x; 1.0188x over previous
//
#include <hip/hip_runtime.h>
#include <math.h>

#define NEG 0.2f
#define EPSV 1e-5f

typedef _Float16 v8h __attribute__((ext_vector_type(8)));
typedef _Float16 v4h __attribute__((ext_vector_type(4)));
typedef _Float16 v2h __attribute__((ext_vector_type(2)));
typedef __fp16   f16x2 __attribute__((ext_vector_type(2)));
typedef float    v4f __attribute__((ext_vector_type(4)));

__device__ __forceinline__ float lrelu(float v) { return fmaxf(v, NEG * v); }
__device__ __forceinline__ v4f lrelu4(v4f v) {
    return __builtin_elementwise_max(v, v * NEG);
}
__device__ __forceinline__ v2h lreluh2(v2h v) {
    return __builtin_elementwise_max(v, v * (_Float16)NEG);
}

// cvt_pkrtz returns __fp16x2; bit-cast to _Float16x2 (same layout)
__device__ __forceinline__ v2h pk(float a, float b) {
    union { f16x2 i; v2h o; } u;
    u.i = __builtin_amdgcn_cvt_pkrtz(a, b);
    return u.o;
}

#define MFMA32(a, b, c) __builtin_amdgcn_mfma_f32_16x16x32_f16((a), (b), (c), 0, 0, 0)
#define MFMA16(a, b, c) __builtin_amdgcn_mfma_f32_16x16x16f16((a), (b), (c), 0, 0, 0)

// Round 14: cross the 2->3 blocks/CU occupancy boundary.
// (1) W2f (32 persistent VGPRs) -> block-shared LDS W2L, stride-40 p-rows
//     (banks (20p+4q)%32: free 2-way only), 8x ds_read_b128 per iter.
// (2) asm memory clobber at loop top so LICM cannot re-hoist the in-loop LDS
//     weight reads back into registers (R9 failure mode).
// (3) XSB dropped (R10/11 showed it ~neutral): per-iter prefetched global
//     loads (L1-resident), saving 20KB LDS -> 38KB total, 4 blocks/CU by LDS.
// Register peak ~115 < (256,3) budget (~170) -> 3 waves/SIMD.
__global__ __launch_bounds__(256, 3)
void gsl_mfma(const float* __restrict__ x,
              const float* __restrict__ trans_w, const float* __restrict__ trans_g,
              const float* __restrict__ trans_b, const float* __restrict__ trans_m,
              const float* __restrict__ trans_v,
              const float* __restrict__ pos_w1, const float* __restrict__ pos_g,
              const float* __restrict__ pos_b, const float* __restrict__ pos_m,
              const float* __restrict__ pos_v, const float* __restrict__ pos_w2,
              const float* __restrict__ pos_b2,
              const float* __restrict__ gate_w1, const float* __restrict__ gate_g,
              const float* __restrict__ gate_b, const float* __restrict__ gate_m,
              const float* __restrict__ gate_v, const float* __restrict__ gate_w2,
              const float* __restrict__ gate_b2,
              const float* __restrict__ attn_w1, const float* __restrict__ attn_g,
              const float* __restrict__ attn_b, const float* __restrict__ attn_m,
              const float* __restrict__ attn_v, const float* __restrict__ attn_w2,
              const float* __restrict__ attn_b2,
              float* __restrict__ out)
{
    __shared__ _Float16 WH[1920];        // WP1 4x(16x20) | WA1 16x20 | WG1 16x20
    __shared__ _Float16 W2L[5120];       // pos_w2 A-frags: 8 tiles x 16p x stride40
    __shared__ float    PB2[64];
    __shared__ _Float16 PHB[4][2][1152]; // per-wave dbuf: 16 pts x stride 72
    __shared__ _Float16 AHB[4][2][320];  // per-wave dbuf: 16 pts x stride 20

    const int tid  = threadIdx.x;
    const int wv   = tid >> 6;
    const int lane = tid & 63;
    const int p    = lane & 15;
    const int q    = lane >> 4;

    const int b  = blockIdx.x >> 7;
    const int n0 = ((blockIdx.x & 127) << 6) | (wv << 4);
    const int n  = n0 | p;

    // ---- stage pos_w2 A-frag layout into W2L (one-time, contiguous reads) ----
    #pragma unroll
    for (int e = 0; e < 16; ++e) {
        int idx = tid * 16 + e;              // 4096 elements
        int t   = idx >> 9;                  // tile (mt*2+h)
        int rem = idx & 511;
        int pp  = rem >> 5;
        int ii  = rem & 31;
        W2L[t * 640 + pp * 40 + ii] =
            (_Float16)pos_w2[((t >> 1) * 16 + pp) * 64 + (t & 1) * 32 + ii];
    }

    // ---- stage produce-side weights in block-shared LDS (rows stride 20h) ----
    if (tid < 64) {
        const int c = tid;
        float sp = pos_g[c] * rsqrtf(pos_v[c] + EPSV);
        float bp = pos_b[c] - pos_m[c] * sp;
        _Float16* row = WH + (c >> 4) * 320 + (c & 15) * 20;
        for (int k = 0; k < 20; ++k) {
            float v = (k >= 3 && k < 6) ? pos_w1[c * 3 + (k - 3)] * sp
                                        : ((k == 6) ? bp : 0.f);
            row[k] = (_Float16)v;
        }
        PB2[c] = pos_b2[c];
    } else if (tid < 80) {
        const int j = tid - 64;
        float sa = attn_g[j] * rsqrtf(attn_v[j] + EPSV);
        float ba = attn_b[j] - attn_m[j] * sa;
        _Float16* row = WH + 1280 + j * 20;
        for (int k = 0; k < 20; ++k)
            row[k] = (_Float16)((k < 6) ? attn_w1[j * 6 + k] * sa
                                        : ((k == 6) ? ba : 0.f));
    } else if (tid < 96) {
        const int j = tid - 80;
        float sg = gate_g[j] * rsqrtf(gate_v[j] + EPSV);
        float bg = gate_b[j] - gate_m[j] * sg;
        _Float16* row = WH + 1600 + j * 20;
        for (int k = 0; k < 20; ++k)
            row[k] = (_Float16)((k < 6) ? gate_w1[j * 6 + k] * sg
                                        : ((k == 6) ? bg : 0.f));
    }

    // ---- persistent A-frags: only WTf/WA2f (K=16, 2 VGPRs each) ----
    v4h WTf[4], WA2f[4];
    #pragma unroll
    for (int mt = 0; mt < 4; ++mt) {
        const int ch = mt * 16 + p;
        #pragma unroll
        for (int i = 0; i < 4; ++i)
            WA2f[mt][i] = (_Float16)attn_w2[ch * 16 + q * 4 + i];
        float st = trans_g[ch] * rsqrtf(trans_v[ch] + EPSV);
        float bt = trans_b[ch] - trans_m[ch] * st;
        #pragma unroll
        for (int i = 0; i < 4; ++i) {
            int k = q * 4 + i;
            float v = (k < 6) ? trans_w[ch * 6 + k] * st : ((k == 6) ? bt : 0.f);
            WTf[mt][i] = (_Float16)v;
        }
    }
    float g2w[4];
    #pragma unroll
    for (int r = 0; r < 4; ++r) g2w[r] = gate_w2[4 * q + r];
    const float gb2v = gate_b2[0];

    __syncthreads();   // W2L/WH/PB2 visible to all waves

    const _Float16* const WP1p = WH + p * 20 + q * 4;          // + mt*320
    const _Float16* const WA1p = WH + 1280 + p * 20 + q * 4;
    const _Float16* const WG1p = WH + 1600 + p * 20 + q * 4;
    const _Float16* const W2Lp = W2L + p * 40 + q * 8;         // + tile*640
    const float* const    PB2p = PB2 + 4 * q;                  // + mt*16

    _Float16* const PHbase = &PHB[wv][0][0];
    _Float16* const AHbase = &AHB[wv][0][0];

    const v4f zero = {0.f, 0.f, 0.f, 0.f};
    v4f den[4], num[4], cmx[4];
    #pragma unroll
    for (int mt = 0; mt < 4; ++mt) {
        den[mt] = zero; num[mt] = zero;
        cmx[mt] = (v4f){-3.4e38f, -3.4e38f, -3.4e38f, -3.4e38f};
    }

    const float* xb = x + ((size_t)(b * 6) * 8192 + n) * 20;
    const int hi = q & 1;   // q>=2 dups q&1 (A-side k>=8 rows are zero)

    // build v4h B-frag for current k from 6 scalars
    float nx[6];
    #pragma unroll
    for (int c = 0; c < 6; ++c) nx[c] = xb[(size_t)c * 163840];

    v4h xv_cur;
    {
        float s0 = hi ? nx[4] : nx[0], s1 = hi ? nx[5] : nx[1];
        float s2 = hi ? 1.f : nx[2],   s3 = hi ? 0.f : nx[3];
        v2h lo = pk(s0, s1), hh = pk(s2, s3);
        xv_cur = (v4h){lo.x, lo.y, hh.x, hh.y};
    }
    #pragma unroll
    for (int c = 0; c < 6; ++c) nx[c] = xb[(size_t)c * 163840 + 1];

    {   // produce(0) into buffer 0
        v4f php[4];
        #pragma unroll
        for (int mt = 0; mt < 4; ++mt)
            php[mt] = MFMA16(*(const v4h*)(WP1p + mt * 320), xv_cur, zero);
        v4f ahp = MFMA16(*(const v4h*)WA1p, xv_cur, zero);
        _Float16* PHW = PHbase + p * 72 + 4 * q;
        #pragma unroll
        for (int mt = 0; mt < 4; ++mt) {
            union { v4h v; v2h h[2]; } u;
            u.h[0] = lreluh2(pk(php[mt][0], php[mt][1]));
            u.h[1] = lreluh2(pk(php[mt][2], php[mt][3]));
            *(v4h*)(PHW + mt * 16) = u.v;
        }
        union { v4h v; v2h h[2]; } ua;
        ua.h[0] = lreluh2(pk(ahp[0], ahp[1]));
        ua.h[1] = lreluh2(pk(ahp[2], ahp[3]));
        *(v4h*)(AHbase + p * 20 + 4 * q) = ua.v;
    }

    #pragma unroll 1
    for (int k = 0; k < 20; ++k) {
        // prevent LICM from hoisting in-loop LDS weight reads into registers
        asm volatile("" ::: "memory");

        const int sel = k & 1;
        // 1) issue reads for k (writes landed last iteration)
        _Float16* PH = PHbase + sel * 1152;
        _Float16* AH = AHbase + sel * 320;
        v8h phf0 = *(const v8h*)(PH + p * 72 + 8 * q);
        v8h phf1 = *(const v8h*)(PH + p * 72 + 32 + 8 * q);
        v4h ahf  = *(const v4h*)(AH + p * 20 + 4 * q);

        // 2) produce(k+1) into the other buffer
        v4h xv_nxt = xv_cur;
        if (k < 19) {
            float s0 = hi ? nx[4] : nx[0], s1 = hi ? nx[5] : nx[1];
            float s2 = hi ? 1.f : nx[2],   s3 = hi ? 0.f : nx[3];
            v2h lo = pk(s0, s1), hh = pk(s2, s3);
            xv_nxt = (v4h){lo.x, lo.y, hh.x, hh.y};
            const int kn = (k < 18) ? k + 2 : 19;
            #pragma unroll
            for (int c = 0; c < 6; ++c) nx[c] = xb[(size_t)c * 163840 + kn];

            v4f php[4];
            #pragma unroll
            for (int mt = 0; mt < 4; ++mt)
                php[mt] = MFMA16(*(const v4h*)(WP1p + mt * 320), xv_nxt, zero);
            v4f ahp = MFMA16(*(const v4h*)WA1p, xv_nxt, zero);
            _Float16* PHW = PHbase + (sel ^ 1) * 1152 + p * 72 + 4 * q;
            #pragma unroll
            for (int mt = 0; mt < 4; ++mt) {
                union { v4h v; v2h h[2]; } uu;
                uu.h[0] = lreluh2(pk(php[mt][0], php[mt][1]));
                uu.h[1] = lreluh2(pk(php[mt][2], php[mt][3]));
                *(v4h*)(PHW + mt * 16) = uu.v;
            }
            union { v4h v; v2h h[2]; } ua;
            ua.h[0] = lreluh2(pk(ahp[0], ahp[1]));
            ua.h[1] = lreluh2(pk(ahp[2], ahp[3]));
            *(v4h*)(AHbase + (sel ^ 1) * 320 + p * 20 + 4 * q) = ua.v;
        }

        // 3) consume(k): gate first (needed by every mt's cmx)
        v4f ghp = MFMA16(*(const v4h*)WG1p, xv_cur, zero);
        float ga = 0.f;
        #pragma unroll
        for (int r = 0; r < 4; ++r) ga += g2w[r] * lrelu(ghp[r]);
        ga += __shfl_xor(ga, 16);
        ga += __shfl_xor(ga, 32);
        const float gate = 1.f / (1.f + __expf(-(ga + gb2v)));

        // per-mt streaming: W2 frags re-read from LDS each iter (clobber holds)
        #pragma unroll
        for (int mt = 0; mt < 4; ++mt) {
            v8h w2a = *(const v8h*)(W2Lp + (mt * 2 + 0) * 640);
            v8h w2b = *(const v8h*)(W2Lp + (mt * 2 + 1) * 640);
            v4f pe = MFMA32(w2a, phf0, *(const v4f*)(PB2p + mt * 16));
            pe = MFMA32(w2b, phf1, pe);
            v4f tfa = MFMA16(WTf[mt], xv_cur, zero);
            v4f tfv = lrelu4(tfa) + pe;
            pe = MFMA16(WA2f[mt], ahf, pe);   // logits (K=16)
            v4f e;
            #pragma unroll
            for (int r = 0; r < 4; ++r) e[r] = __expf(pe[r]);
            den[mt] += e;
            num[mt] += tfv * e;
            cmx[mt] = __builtin_elementwise_max(cmx[mt], tfv * gate);
        }
        xv_cur = xv_nxt;
    }

    // write out: lane owns channels mt*16 + 4q + r for its point n
    #pragma unroll
    for (int mt = 0; mt < 4; ++mt) {
        #pragma unroll
        for (int r = 0; r < 4; ++r) {
            const int ch = mt * 16 + 4 * q + r;
            out[((size_t)(b * 64 + ch)) * 8192 + n] =
                num[mt][r] / den[mt][r] + cmx[mt][r];
        }
    }
}

extern "C" void kernel_launch(void* const* d_in, const int* in_sizes, int n_in,
                              void* d_out, int out_size, void* d_ws, size_t ws_size,
                              hipStream_t stream) {
    const float* x       = (const float*)d_in[0];
    const float* trans_w = (const float*)d_in[1];
    const float* trans_g = (const float*)d_in[2];
    const float* trans_b = (const float*)d_in[3];
    const float* trans_m = (const float*)d_in[4];
    const float* trans_v = (const float*)d_in[5];
    const float* pos_w1  = (const float*)d_in[6];
    const float* pos_g   = (const float*)d_in[7];
    const float* pos_b   = (const float*)d_in[8];
    const float* pos_m   = (const float*)d_in[9];
    const float* pos_v   = (const float*)d_in[10];
    const float* pos_w2  = (const float*)d_in[11];
    const float* pos_b2  = (const float*)d_in[12];
    const float* gate_w1 = (const float*)d_in[13];
    const float* gate_g  = (const float*)d_in[14];
    const float* gate_b  = (const float*)d_in[15];
    const float* gate_m  = (const float*)d_in[16];
    const float* gate_v  = (const float*)d_in[17];
    const float* gate_w2 = (const float*)d_in[18];
    const float* gate_b2 = (const float*)d_in[19];
    const float* attn_w1 = (const float*)d_in[20];
    const float* attn_g  = (const float*)d_in[21];
    const float* attn_b  = (const float*)d_in[22];
    const float* attn_m  = (const float*)d_in[23];
    const float* attn_v  = (const float*)d_in[24];
    const float* attn_w2 = (const float*)d_in[25];
    const float* attn_b2 = (const float*)d_in[26];
    float* out = (float*)d_out;

    // 8 b * 128 blocks/b; block = 4 waves * 16 points
    gsl_mfma<<<1024, 256, 0, stream>>>(
        x, trans_w, trans_g, trans_b, trans_m, trans_v,
        pos_w1, pos_g, pos_b, pos_m, pos_v, pos_w2, pos_b2,
        gate_w1, gate_g, gate_b, gate_m, gate_v, gate_w2, gate_b2,
        attn_w1, attn_g, attn_b, attn_m, attn_v, attn_w2, attn_b2,
        out);
}